// Round 1
// baseline (1455.347 us; speedup 1.0000x reference)
//
#include <hip/hip_runtime.h>
#include <math.h>

#define S_   400
#define B_   16
#define T_   32
#define H_   256
#define A_   100
#define G_   50
#define VF_  100
#define V_   50000
#define BV_  50050

#define L2E   1.44269504088896f
#define L2E2  2.88539008177793f

// ---- ws offsets (in floats) ----
#define WS_H0S   0          // [2][B][H] parity-buffered layer0 h
#define WS_C0S   8192
#define WS_H1S   16384
#define WS_C1S   24576
#define WS_Y0    32768      // [T][B][H] layer0 outputs
#define WS_OD    163840     // [T][B][H] layer1 outputs (output_dec)
#define WS_WT0   294912     // [256][1024] w_hh0^T
#define WS_WTI1  557056     // [256][1024] w_ih1^T
#define WS_WTH1  819200     // [256][1024] w_hh1^T
#define WS_WODT  1081344    // [256][100]  W_attn[:,512:768]^T
#define WS_WV1T  1106944    // [768][100]  W_v1^T
#define WS_WRT   1183744    // [512][256]  W_reduce^T
#define WS_BASE2 1314816    // [B][A][S]  (enc@Wattn + b_attn)*2log2e
#define WS_ODP2  1954816    // [T][B][A]
#define WS_ATTN  2006016    // [B][S][T]
#define WS_CTX   2210816    // [2][T][B][512] two s-half partials
#define WS_H1V   2735104    // [T*B][100]
#define WS_PGEN  2786304    // [T*B]
#define WS_RMAX  2786816    // [T*B]
#define WS_RINV  2787328    // [T*B]
#define WS_TOTAL 2787840

// ---- out offsets (floats) ----
#define OUT_CL   25625600
#define OUT_COV  25626112
#define OUT_HID  25632512
#define OUT_CELL 25640704

__device__ __forceinline__ float fexp2(float x){ return __builtin_amdgcn_exp2f(x); }
__device__ __forceinline__ float frcp (float x){ return __builtin_amdgcn_rcpf(x); }
__device__ __forceinline__ float sigm (float x){ return frcp(1.f + fexp2(-L2E*x)); }
__device__ __forceinline__ float tanhx(float x){ return fmaf(-2.f, frcp(1.f + fexp2(L2E2*x)), 1.f); }

__device__ __forceinline__ float bredSum(float v, float* red){
  #pragma unroll
  for (int m = 32; m >= 1; m >>= 1) v += __shfl_xor(v, m);
  __syncthreads();
  if ((threadIdx.x & 63) == 0) red[threadIdx.x >> 6] = v;
  __syncthreads();
  float r = 0.f;
  int nw = blockDim.x >> 6;
  for (int k = 0; k < nw; ++k) r += red[k];
  return r;
}
__device__ __forceinline__ float bredMax(float v, float* red){
  #pragma unroll
  for (int m = 32; m >= 1; m >>= 1) v = fmaxf(v, __shfl_xor(v, m));
  __syncthreads();
  if ((threadIdx.x & 63) == 0) red[threadIdx.x >> 6] = v;
  __syncthreads();
  float r = -INFINITY;
  int nw = blockDim.x >> 6;
  for (int k = 0; k < nw; ++k) r = fmaxf(r, red[k]);
  return r;
}

// ---------------- weight transposes ----------------
__global__ __launch_bounds__(256) void k_prep(const float* __restrict__ w_hh0,
    const float* __restrict__ w_ih1, const float* __restrict__ w_hh1,
    const float* __restrict__ W_attn, const float* __restrict__ W_v1,
    const float* __restrict__ W_reduce, float* __restrict__ ws){
  int i = blockIdx.x*256 + threadIdx.x;
  if (i < 262144){ int k = i >> 10, j = i & 1023; ws[WS_WT0 + i] = w_hh0[j*256 + k]; return; }
  i -= 262144;
  if (i < 262144){ int k = i >> 10, j = i & 1023; ws[WS_WTI1 + i] = w_ih1[j*256 + k]; return; }
  i -= 262144;
  if (i < 262144){ int k = i >> 10, j = i & 1023; ws[WS_WTH1 + i] = w_hh1[j*256 + k]; return; }
  i -= 262144;
  if (i < 25600){ int k = i/100, a = i%100; ws[WS_WODT + i] = W_attn[a*769 + 512 + k]; return; }
  i -= 25600;
  if (i < 76800){ int k = i/100, f = i%100; ws[WS_WV1T + i] = W_v1[f*768 + k]; return; }
  i -= 76800;
  if (i < 131072){ int k = i >> 8, j = i & 255; ws[WS_WRT + i] = W_reduce[j*512 + k]; return; }
}

// ---------------- encoder state reduce ----------------
__global__ __launch_bounds__(256) void k_reduce_enc(const float* __restrict__ he,
    const float* __restrict__ ce, const float* __restrict__ b_reduce, float* __restrict__ ws){
  int bx = blockIdx.x;            // 32 blocks: l = bx>>4, b = bx&15
  int l = bx >> 4, b = bx & 15, j = threadIdx.x;
  const float* wrt = ws + WS_WRT;
  const float* h_a = he + (l*B_ + b)*H_;
  const float* h_b = he + ((l+2)*B_ + b)*H_;
  const float* c_a = ce + (l*B_ + b)*H_;
  const float* c_b = ce + ((l+2)*B_ + b)*H_;
  float ah = b_reduce[j], ac = b_reduce[j];
  for (int k = 0; k < 256; ++k){
    float w0 = wrt[k*256 + j];
    float w1 = wrt[(256+k)*256 + j];
    ah += w0*h_a[k] + w1*h_b[k];
    ac += w0*c_a[k] + w1*c_b[k];
  }
  if (l == 0){ ws[WS_H0S + b*256 + j] = ah; ws[WS_C0S + b*256 + j] = ac; }
  else       { ws[WS_H1S + b*256 + j] = ah; ws[WS_C1S + b*256 + j] = ac; }
}

// ---------------- enc_base = (output_enc @ W_attn[:, :512]^T + b_attn)*2log2e ----------------
__global__ __launch_bounds__(256) void k_enc_base(const float* __restrict__ enc,
    const float* __restrict__ W_attn, const float* __restrict__ b_attn, float* __restrict__ ws){
  int st = blockIdx.x, ah = blockIdx.y, b = blockIdx.z;   // (25, 2, 16)
  int s_base = st*16;
  __shared__ float encs[16][132];
  __shared__ float was[50][132];
  int tid = threadIdx.x;
  bool act = tid < 200;
  int sg = tid & 7, ag = tid >> 3;     // sg<8, ag<25 when act
  int sl = sg*2, al = ag*2;
  float acc00=0.f, acc01=0.f, acc10=0.f, acc11=0.f;
  for (int kc = 0; kc < 4; ++kc){
    int k0 = kc*128;
    __syncthreads();
    for (int o = tid; o < 512; o += 256){
      int r = o >> 5, c4 = (o & 31)*4;
      float4 v = *(const float4*)(enc + ((s_base + r)*B_ + b)*512 + k0 + c4);
      *(float4*)&encs[r][c4] = v;
    }
    for (int o = tid; o < 6400; o += 256){
      int r = o >> 7, c = o & 127;
      was[r][c] = W_attn[(ah*50 + r)*769 + k0 + c];
    }
    __syncthreads();
    if (act){
      for (int k = 0; k < 128; ++k){
        float e0 = encs[sl][k], e1 = encs[sl+1][k];
        float w0 = was[al][k],  w1 = was[al+1][k];
        acc00 = fmaf(e0, w0, acc00); acc01 = fmaf(e0, w1, acc01);
        acc10 = fmaf(e1, w0, acc10); acc11 = fmaf(e1, w1, acc11);
      }
    }
  }
  if (act){
    int a = ah*50 + al, s = s_base + sl;
    float* bp = ws + WS_BASE2 + (b*A_)*S_;
    bp[(a  )*S_ + s  ] = (acc00 + b_attn[a  ]) * L2E2;
    bp[(a+1)*S_ + s  ] = (acc01 + b_attn[a+1]) * L2E2;
    bp[(a  )*S_ + s+1] = (acc10 + b_attn[a  ]) * L2E2;
    bp[(a+1)*S_ + s+1] = (acc11 + b_attn[a+1]) * L2E2;
  }
}

// ---------------- LSTM phase p: WGs 0-63 = layer0 step p, WGs 64-127 = layer1 step p-1 ----------------
__global__ __launch_bounds__(256) void k_lstm(const float* __restrict__ input_dec,
    const float* __restrict__ w_ih0, const float* __restrict__ b_ih0, const float* __restrict__ b_hh0,
    const float* __restrict__ b_ih1, const float* __restrict__ b_hh1,
    float* __restrict__ ws, float* __restrict__ out, int p){
  int w = blockIdx.x;
  int tid = threadIdx.x;
  int wl = w & 63;
  int b = wl & 15, hb = wl >> 4;
  int gate = tid >> 6, hl = tid & 63, hidx = hb*64 + hl;
  int j = gate*256 + hidx;
  __shared__ float hs[256], ys[256], gv[4][64];
  if (w < 64){
    if (p >= T_) return;
    int par = p & 1, npar = par ^ 1;
    hs[tid] = ws[WS_H0S + par*4096 + b*256 + tid];
    __syncthreads();
    float x = input_dec[p*16 + b];
    float acc = fmaf(x, w_ih0[j], b_ih0[j] + b_hh0[j]);
    const float* wt = ws + WS_WT0 + j;
    #pragma unroll 4
    for (int k = 0; k < 256; ++k) acc = fmaf(wt[k*1024], hs[k], acc);
    gv[gate][hl] = acc;
    __syncthreads();
    if (gate == 0){
      float ig = sigm(gv[0][hl]), fg = sigm(gv[1][hl]);
      float gg = tanhx(gv[2][hl]), og = sigm(gv[3][hl]);
      float cold = ws[WS_C0S + par*4096 + b*256 + hidx];
      float cn = fmaf(fg, cold, ig*gg);
      float hn = og * tanhx(cn);
      ws[WS_C0S + npar*4096 + b*256 + hidx] = cn;
      ws[WS_H0S + npar*4096 + b*256 + hidx] = hn;
      ws[WS_Y0 + (p*16 + b)*256 + hidx] = hn;
      if (p == T_-1){
        out[OUT_HID  + b*256 + hidx] = hn;
        out[OUT_CELL + b*256 + hidx] = cn;
      }
    }
  } else {
    int q = p - 1;
    if (q < 0) return;
    int par = q & 1, npar = par ^ 1;
    hs[tid] = ws[WS_H1S + par*4096 + b*256 + tid];
    ys[tid] = ws[WS_Y0 + (q*16 + b)*256 + tid];
    __syncthreads();
    float acc = b_ih1[j] + b_hh1[j];
    const float* wi = ws + WS_WTI1 + j;
    const float* wh = ws + WS_WTH1 + j;
    #pragma unroll 2
    for (int k = 0; k < 256; ++k){
      acc = fmaf(wi[k*1024], ys[k], acc);
      acc = fmaf(wh[k*1024], hs[k], acc);
    }
    gv[gate][hl] = acc;
    __syncthreads();
    if (gate == 0){
      float ig = sigm(gv[0][hl]), fg = sigm(gv[1][hl]);
      float gg = tanhx(gv[2][hl]), og = sigm(gv[3][hl]);
      float cold = ws[WS_C1S + par*4096 + b*256 + hidx];
      float cn = fmaf(fg, cold, ig*gg);
      float hn = og * tanhx(cn);
      ws[WS_C1S + npar*4096 + b*256 + hidx] = cn;
      ws[WS_H1S + npar*4096 + b*256 + hidx] = hn;
      ws[WS_OD + (q*16 + b)*256 + hidx] = hn;
      if (q == T_-1){
        out[OUT_HID  + 4096 + b*256 + hidx] = hn;
        out[OUT_CELL + 4096 + b*256 + hidx] = cn;
      }
    }
  }
}

// ---------------- odp2[t][b][a] = (od @ W_attn[:,512:768]^T) * 2log2e ----------------
__global__ __launch_bounds__(256) void k_odp(float* __restrict__ ws){
  int row = blockIdx.x;        // 512 = t*16+b
  int tid = threadIdx.x;
  __shared__ float odl[256];
  odl[tid] = ws[WS_OD + row*256 + tid];
  __syncthreads();
  if (tid < 100){
    float acc = 0.f;
    for (int k = 0; k < 256; ++k) acc = fmaf(ws[WS_WODT + k*100 + tid], odl[k], acc);
    ws[WS_ODP2 + row*100 + tid] = acc * L2E2;
  }
}

// ---------------- attention recurrence: one WG per batch element ----------------
__global__ __launch_bounds__(1024) void k_attn(const float* __restrict__ amask,
    const float* __restrict__ W_attn, const float* __restrict__ wout_g,
    float* __restrict__ out, float* __restrict__ ws){
  int b = blockIdx.x;
  int tid = threadIdx.x;
  __shared__ float cov[400], ev[400], am[400], odp_l[100], wc2[100], wo[100], red[16];
  if (tid < 400){ cov[tid] = 0.f; am[tid] = amask[tid*16 + b]; }
  if (tid < 100){ wc2[tid] = W_attn[tid*769 + 768] * L2E2; wo[tid] = wout_g[tid]; }
  const float* base2 = ws + WS_BASE2 + b*A_*S_;
  int s = tid >> 1, half = tid & 1;
  for (int t = 0; t < T_; ++t){
    if (tid < 100) odp_l[tid] = ws[WS_ODP2 + (t*16 + b)*100 + tid];
    __syncthreads();
    float e = 0.f;
    if (s < 400){
      float cv = cov[s];
      int a0 = half*50;
      #pragma unroll 5
      for (int a = a0; a < a0 + 50; ++a){
        float s1 = base2[a*400 + s] + odp_l[a];
        float x  = fmaf(wc2[a], cv, s1);
        float r  = frcp(1.f + fexp2(x));
        float th = fmaf(-2.f, r, 1.f);
        e = fmaf(wo[a], th, e);
      }
    }
    e += __shfl_xor(e, 1);
    if (s < 400 && half == 0) ev[s] = e + am[s];
    __syncthreads();
    float v = (tid < 400) ? ev[tid] : -INFINITY;
    float mx = bredMax(v, red);
    float ex = (tid < 400) ? fexp2((ev[tid] - mx) * L2E) : 0.f;
    float sm = bredSum(ex, red);
    float inv = frcp(sm);
    float at = ex * inv;
    float cl = (tid < 400) ? fminf(at, cov[tid]) : 0.f;
    float cls = bredSum(cl, red);
    if (tid < 400){
      cov[tid] += at;
      ws[WS_ATTN + (b*400 + tid)*32 + t] = at;
    }
    if (tid == 0) out[OUT_CL + t*16 + b] = cls;
    __syncthreads();
  }
  if (tid < 400) out[OUT_COV + tid*16 + b] = cov[tid];
}

// ---------------- context partials: ctx[sh][t][b][j] = sum_{s in half} attn*enc ----------------
__global__ __launch_bounds__(256) void k_ctx(const float* __restrict__ enc,
    const float* __restrict__ attn, float* __restrict__ ctx){
  int b = blockIdx.x, jh = blockIdx.y, sh = blockIdx.z;   // (16,2,2)
  int j = jh*256 + threadIdx.x;
  float acc[32];
  #pragma unroll
  for (int t = 0; t < 32; ++t) acc[t] = 0.f;
  const float* ap0 = attn + b*400*32;
  for (int s = sh*200; s < sh*200 + 200; ++s){
    float evv = enc[(s*16 + b)*512 + j];
    const float* ap = ap0 + s*32;
    #pragma unroll
    for (int t = 0; t < 32; ++t) acc[t] = fmaf(ap[t], evv, acc[t]);
  }
  #pragma unroll
  for (int t = 0; t < 32; ++t) ctx[sh*262144 + (t*16 + b)*512 + j] = acc[t];
}

// ---------------- pgen + h1 (vocab hidden) per (t,b) ----------------
__global__ __launch_bounds__(256) void k_pgen_h1(const float* __restrict__ input_dec,
    const float* __restrict__ emb, const float* __restrict__ b_v1,
    const float* __restrict__ W_pgen, const float* __restrict__ b_pgen,
    float* __restrict__ ws){
  int row = blockIdx.x, tid = threadIdx.x;
  __shared__ float pv[768], el[50], red[16];
  pv[tid]       = ws[WS_OD + row*256 + tid];
  pv[256 + tid] = ws[WS_CTX + row*512 + tid]       + ws[WS_CTX + 262144 + row*512 + tid];
  pv[512 + tid] = ws[WS_CTX + row*512 + 256 + tid] + ws[WS_CTX + 262144 + row*512 + 256 + tid];
  int tok = (int)input_dec[row];
  if (tid < 50) el[tid] = emb[tok*50 + tid];
  __syncthreads();
  float p = 0.f;
  for (int k = tid; k < 818; k += 256){
    float x = (k < 512) ? pv[256 + k] : (k < 768) ? pv[k - 512] : el[k - 768];
    p = fmaf(W_pgen[k], x, p);
  }
  p = bredSum(p, red);
  if (tid == 0) ws[WS_PGEN + row] = sigm(p + b_pgen[0]);
  if (tid < 100){
    float acc = b_v1[tid];
    for (int k = 0; k < 768; ++k) acc = fmaf(ws[WS_WV1T + k*100 + tid], pv[k], acc);
    ws[WS_H1V + row*100 + tid] = acc;
  }
}

// ---------------- logits = h1 @ W_v2^T + b_v2, written into out pvocab region ----------------
__global__ __launch_bounds__(256) void k_logits(const float* __restrict__ W_v2,
    const float* __restrict__ b_v2, const float* __restrict__ ws, float* __restrict__ out){
  int chunk = blockIdx.x, rblk = blockIdx.y;   // (391, 8)
  int vbase = chunk*128, rbase = rblk*64;
  __shared__ float h1l[100][68];
  __shared__ float wl[100][132];
  int tid = threadIdx.x;
  for (int o = tid; o < 6400; o += 256){
    int r = o/100, f = o%100;
    h1l[f][r] = ws[WS_H1V + (rbase + r)*100 + f];
  }
  for (int o = tid; o < 12800; o += 256){
    int vl = o/100, f = o%100;
    int v = vbase + vl;
    wl[f][vl] = (v < V_) ? W_v2[v*100 + f] : 0.f;
  }
  __syncthreads();
  int vb = (tid & 15)*8, rb = (tid >> 4)*4;
  float acc[4][8];
  #pragma unroll
  for (int i = 0; i < 4; ++i)
    #pragma unroll
    for (int jj = 0; jj < 8; ++jj) acc[i][jj] = 0.f;
  for (int f = 0; f < 100; ++f){
    float4 h4 = *(const float4*)&h1l[f][rb];
    float4 w0 = *(const float4*)&wl[f][vb];
    float4 w1 = *(const float4*)&wl[f][vb+4];
    float hv[4] = {h4.x, h4.y, h4.z, h4.w};
    float wv[8] = {w0.x, w0.y, w0.z, w0.w, w1.x, w1.y, w1.z, w1.w};
    #pragma unroll
    for (int i = 0; i < 4; ++i)
      #pragma unroll
      for (int jj = 0; jj < 8; ++jj) acc[i][jj] = fmaf(hv[i], wv[jj], acc[i][jj]);
  }
  float bv[8];
  #pragma unroll
  for (int jj = 0; jj < 8; ++jj){
    int v = vbase + vb + jj;
    bv[jj] = (v < V_) ? b_v2[v] : 0.f;
  }
  #pragma unroll
  for (int i = 0; i < 4; ++i){
    int row = rbase + rb + i;
    int base = row*BV_ + vbase + vb;
    if (chunk < 390){
      #pragma unroll
      for (int j2 = 0; j2 < 4; ++j2){
        float2 val;
        val.x = acc[i][2*j2]   + bv[2*j2];
        val.y = acc[i][2*j2+1] + bv[2*j2+1];
        *(float2*)&out[base + 2*j2] = val;
      }
    } else {
      for (int jj = 0; jj < 8; ++jj){
        int v = vbase + vb + jj;
        if (v < V_) out[row*BV_ + v] = acc[i][jj] + bv[jj];
      }
    }
  }
}

// ---------------- per-row online max/sum of exp ----------------
__global__ __launch_bounds__(256) void k_rowstats(const float* __restrict__ out, float* __restrict__ ws){
  int row = blockIdx.x, tid = threadIdx.x;
  float m = -INFINITY, s = 0.f;
  for (int v = tid; v < V_; v += 256){
    float l = out[row*BV_ + v];
    float M = fmaxf(m, l);
    s = s*fexp2((m - M)*L2E) + fexp2((l - M)*L2E);
    m = M;
  }
  #pragma unroll
  for (int msk = 32; msk >= 1; msk >>= 1){
    float m2 = __shfl_xor(m, msk), s2 = __shfl_xor(s, msk);
    float M = fmaxf(m, m2);
    s = s*fexp2((m - M)*L2E) + s2*fexp2((m2 - M)*L2E);
    m = M;
  }
  __shared__ float rm[4], rs[4];
  int wid = tid >> 6, lane = tid & 63;
  if (lane == 0){ rm[wid] = m; rs[wid] = s; }
  __syncthreads();
  if (tid == 0){
    float m0 = rm[0], s0 = rs[0];
    for (int w2 = 1; w2 < 4; ++w2){
      float M = fmaxf(m0, rm[w2]);
      s0 = s0*fexp2((m0 - M)*L2E) + rs[w2]*fexp2((rm[w2] - M)*L2E);
      m0 = M;
    }
    ws[WS_RMAX + row] = m0;
    ws[WS_RINV + row] = 1.f / s0;
  }
}

// ---------------- in-place softmax * pgen + zero pad ----------------
__global__ __launch_bounds__(256) void k_finalize(float* __restrict__ out, const float* __restrict__ ws){
  int row = blockIdx.y;
  float M  = ws[WS_RMAX + row];
  float sc = ws[WS_RINV + row] * ws[WS_PGEN + row];
  int v4 = (blockIdx.x*256 + threadIdx.x)*4;
  if (v4 < V_){
    float2* p0 = (float2*)&out[row*BV_ + v4];
    float2 a = p0[0], b2 = p0[1];
    a.x  = fexp2((a.x  - M)*L2E)*sc;
    a.y  = fexp2((a.y  - M)*L2E)*sc;
    b2.x = fexp2((b2.x - M)*L2E)*sc;
    b2.y = fexp2((b2.y - M)*L2E)*sc;
    p0[0] = a; p0[1] = b2;
  }
  if (blockIdx.x == 49 && threadIdx.x < 50) out[row*BV_ + V_ + threadIdx.x] = 0.f;
}

// ---------------- copy-distribution scatter ----------------
__global__ __launch_bounds__(256) void k_scatter(const int* __restrict__ real_index,
    const float* __restrict__ ws, float* __restrict__ out){
  int i = blockIdx.x*256 + threadIdx.x;   // < 16*400*32
  int b = i / 12800, r = i % 12800, s = r >> 5, t = r & 31;
  float at = ws[WS_ATTN + i];
  float w = 1.f - ws[WS_PGEN + t*16 + b];
  int col = real_index[s*16 + b];
  atomicAdd(out + (t*16 + b)*BV_ + col, at*w);
}

extern "C" void kernel_launch(void* const* d_in, const int* in_sizes, int n_in,
                              void* d_out, int out_size, void* d_ws, size_t ws_size,
                              hipStream_t stream){
  const float* output_enc = (const float*)d_in[0];
  const int*   real_index = (const int*)d_in[1];
  const float* input_dec  = (const float*)d_in[3];
  const float* hidden_enc = (const float*)d_in[4];
  const float* cell_enc   = (const float*)d_in[5];
  const float* att_mask   = (const float*)d_in[6];
  const float* emb        = (const float*)d_in[7];
  const float* b_reduce   = (const float*)d_in[9];
  const float* w_ih0      = (const float*)d_in[10];
  const float* w_hh0      = (const float*)d_in[11];
  const float* b_ih0      = (const float*)d_in[12];
  const float* b_hh0      = (const float*)d_in[13];
  const float* w_ih1      = (const float*)d_in[14];
  const float* w_hh1      = (const float*)d_in[15];
  const float* b_ih1      = (const float*)d_in[16];
  const float* b_hh1      = (const float*)d_in[17];
  const float* W_attn     = (const float*)d_in[18];
  const float* b_attn     = (const float*)d_in[19];
  const float* w_attn_out = (const float*)d_in[20];
  const float* W_v1       = (const float*)d_in[21];
  const float* b_v1       = (const float*)d_in[22];
  const float* W_v2       = (const float*)d_in[23];
  const float* b_v2       = (const float*)d_in[24];
  const float* W_pgen     = (const float*)d_in[25];
  const float* b_pgen     = (const float*)d_in[26];
  const float* W_reduce   = (const float*)d_in[8];
  float* out = (float*)d_out;
  float* ws  = (float*)d_ws;
  if (ws_size < (size_t)WS_TOTAL * sizeof(float)) return;

  k_prep<<<dim3(3984), dim3(256), 0, stream>>>(w_hh0, w_ih1, w_hh1, W_attn, W_v1, W_reduce, ws);
  k_reduce_enc<<<dim3(32), dim3(256), 0, stream>>>(hidden_enc, cell_enc, b_reduce, ws);
  k_enc_base<<<dim3(25, 2, 16), dim3(256), 0, stream>>>(output_enc, W_attn, b_attn, ws);
  for (int p = 0; p <= T_; ++p)
    k_lstm<<<dim3(128), dim3(256), 0, stream>>>(input_dec, w_ih0, b_ih0, b_hh0, b_ih1, b_hh1, ws, out, p);
  k_odp<<<dim3(512), dim3(256), 0, stream>>>(ws);
  k_attn<<<dim3(16), dim3(1024), 0, stream>>>(att_mask, W_attn, w_attn_out, out, ws);
  k_ctx<<<dim3(16, 2, 2), dim3(256), 0, stream>>>(output_enc, ws + WS_ATTN, ws + WS_CTX);
  k_pgen_h1<<<dim3(512), dim3(256), 0, stream>>>(input_dec, emb, b_v1, W_pgen, b_pgen, ws);
  k_logits<<<dim3(391, 8), dim3(256), 0, stream>>>(W_v2, b_v2, ws, out);
  k_rowstats<<<dim3(512), dim3(256), 0, stream>>>(out, ws);
  k_finalize<<<dim3(50, 512), dim3(256), 0, stream>>>(out, ws);
  k_scatter<<<dim3(800), dim3(256), 0, stream>>>(real_index, ws, out);
}

// Round 2
// 1299.639 us; speedup vs baseline: 1.1198x; 1.1198x over previous
//
#include <hip/hip_runtime.h>
#include <math.h>

#define S_   400
#define B_   16
#define T_   32
#define H_   256
#define A_   100
#define G_   50
#define VF_  100
#define V_   50000
#define BV_  50050

#define L2E   1.44269504088896f
#define L2E2  2.88539008177793f

// ---- ws offsets (in floats) ----
#define WS_H0S   0          // [2][B][H] parity-buffered layer0 h
#define WS_C0S   8192
#define WS_H1S   16384
#define WS_C1S   24576
#define WS_Y0    32768      // [T][B][H] layer0 outputs
#define WS_OD    163840     // [T][B][H] layer1 outputs (output_dec)
#define WS_WODT  294912     // [256][100]  W_attn[:,512:768]^T
#define WS_WV1T  320512     // [768][100]  W_v1^T
#define WS_WRT   397312     // [512][256]  W_reduce^T
#define WS_BASE2 528384     // [B][A][S]  (enc@Wattn + b_attn)*2log2e
#define WS_ODP2  1168384    // [T][B][A]
#define WS_ATTN  1219584    // [B][S][T]
#define WS_CTX   1424384    // [2][T][B][512] two s-half partials
#define WS_H1V   1948672    // [T*B][100]
#define WS_PGEN  1999872    // [T*B]
#define WS_VSUM  2000384    // [T*B] vocab exp-sums
#define WS_ESUM  2000896    // [T][B] attention exp-sums
#define WS_FLAG  2001408    // [T][B] int flags
#define WS_TOTAL 2001920

// ---- out offsets (floats) ----
#define OUT_CL   25625600
#define OUT_COV  25626112
#define OUT_HID  25632512
#define OUT_CELL 25640704

__device__ __forceinline__ float fexp2(float x){ return __builtin_amdgcn_exp2f(x); }
__device__ __forceinline__ float frcp (float x){ return __builtin_amdgcn_rcpf(x); }
__device__ __forceinline__ float sigm (float x){ return frcp(1.f + fexp2(-L2E*x)); }
__device__ __forceinline__ float tanhx(float x){ return fmaf(-2.f, frcp(1.f + fexp2(L2E2*x)), 1.f); }

__device__ __forceinline__ float bredSum(float v, float* red){
  #pragma unroll
  for (int m = 32; m >= 1; m >>= 1) v += __shfl_xor(v, m);
  __syncthreads();
  if ((threadIdx.x & 63) == 0) red[threadIdx.x >> 6] = v;
  __syncthreads();
  float r = 0.f;
  int nw = blockDim.x >> 6;
  for (int k = 0; k < nw; ++k) r += red[k];
  return r;
}

// ---------------- small transposes + zeroing ----------------
__global__ __launch_bounds__(256) void k_prep(const float* __restrict__ W_attn,
    const float* __restrict__ W_v1, const float* __restrict__ W_reduce,
    float* __restrict__ out, float* __restrict__ ws){
  int i = blockIdx.x*256 + threadIdx.x;
  if (i < 25600){ int k = i/100, a = i%100; ws[WS_WODT + i] = W_attn[a*769 + 512 + k]; return; }
  i -= 25600;
  if (i < 76800){ int k = i/100, f = i%100; ws[WS_WV1T + i] = W_v1[f*768 + k]; return; }
  i -= 76800;
  if (i < 131072){ int k = i >> 8, j = i & 255; ws[WS_WRT + i] = W_reduce[j*512 + k]; return; }
  i -= 131072;
  if (i < 512){ ((int*)(ws + WS_FLAG))[i] = 0; return; }
  i -= 512;
  if (i < 512){ ws[WS_ESUM + i] = 0.f; return; }
  i -= 512;
  if (i < 512){ ws[WS_VSUM + i] = 0.f; return; }
  i -= 512;
  if (i < 512){ out[OUT_CL + i] = 0.f; return; }
}

// ---------------- encoder state reduce ----------------
__global__ __launch_bounds__(256) void k_reduce_enc(const float* __restrict__ he,
    const float* __restrict__ ce, const float* __restrict__ b_reduce, float* __restrict__ ws){
  int bx = blockIdx.x;            // 32 blocks: l = bx>>4, b = bx&15
  int l = bx >> 4, b = bx & 15, j = threadIdx.x;
  const float* wrt = ws + WS_WRT;
  const float* h_a = he + (l*B_ + b)*H_;
  const float* h_b = he + ((l+2)*B_ + b)*H_;
  const float* c_a = ce + (l*B_ + b)*H_;
  const float* c_b = ce + ((l+2)*B_ + b)*H_;
  float ah = b_reduce[j], ac = b_reduce[j];
  for (int k = 0; k < 256; ++k){
    float w0 = wrt[k*256 + j];
    float w1 = wrt[(256+k)*256 + j];
    ah += w0*h_a[k] + w1*h_b[k];
    ac += w0*c_a[k] + w1*c_b[k];
  }
  if (l == 0){ ws[WS_H0S + b*256 + j] = ah; ws[WS_C0S + b*256 + j] = ac; }
  else       { ws[WS_H1S + b*256 + j] = ah; ws[WS_C1S + b*256 + j] = ac; }
}

// ---------------- enc_base = (output_enc @ W_attn[:, :512]^T + b_attn)*2log2e ----------------
__global__ __launch_bounds__(256) void k_enc_base(const float* __restrict__ enc,
    const float* __restrict__ W_attn, const float* __restrict__ b_attn, float* __restrict__ ws){
  int st = blockIdx.x, ah = blockIdx.y, b = blockIdx.z;   // (25, 2, 16)
  int s_base = st*16;
  __shared__ float encs[16][132];
  __shared__ float was[50][132];
  int tid = threadIdx.x;
  bool act = tid < 200;
  int sg = tid & 7, ag = tid >> 3;     // sg<8, ag<25 when act
  int sl = sg*2, al = ag*2;
  float acc00=0.f, acc01=0.f, acc10=0.f, acc11=0.f;
  for (int kc = 0; kc < 4; ++kc){
    int k0 = kc*128;
    __syncthreads();
    for (int o = tid; o < 512; o += 256){
      int r = o >> 5, c4 = (o & 31)*4;
      float4 v = *(const float4*)(enc + ((s_base + r)*B_ + b)*512 + k0 + c4);
      *(float4*)&encs[r][c4] = v;
    }
    for (int o = tid; o < 6400; o += 256){
      int r = o >> 7, c = o & 127;
      was[r][c] = W_attn[(ah*50 + r)*769 + k0 + c];
    }
    __syncthreads();
    if (act){
      for (int k = 0; k < 128; ++k){
        float e0 = encs[sl][k], e1 = encs[sl+1][k];
        float w0 = was[al][k],  w1 = was[al+1][k];
        acc00 = fmaf(e0, w0, acc00); acc01 = fmaf(e0, w1, acc01);
        acc10 = fmaf(e1, w0, acc10); acc11 = fmaf(e1, w1, acc11);
      }
    }
  }
  if (act){
    int a = ah*50 + al, s = s_base + sl;
    float* bpp = ws + WS_BASE2 + (b*A_)*S_;
    bpp[(a  )*S_ + s  ] = (acc00 + b_attn[a  ]) * L2E2;
    bpp[(a+1)*S_ + s  ] = (acc01 + b_attn[a+1]) * L2E2;
    bpp[(a  )*S_ + s+1] = (acc10 + b_attn[a  ]) * L2E2;
    bpp[(a+1)*S_ + s+1] = (acc11 + b_attn[a+1]) * L2E2;
  }
}

// ---------------- LSTM phase p: WGs 0-63 = layer0 step p, WGs 64-127 = layer1 step p-1 ----------------
__global__ __launch_bounds__(256) void k_lstm(const float* __restrict__ input_dec,
    const float* __restrict__ w_ih0, const float* __restrict__ w_hh0,
    const float* __restrict__ b_ih0, const float* __restrict__ b_hh0,
    const float* __restrict__ w_ih1, const float* __restrict__ w_hh1,
    const float* __restrict__ b_ih1, const float* __restrict__ b_hh1,
    float* __restrict__ ws, float* __restrict__ out, int p){
  int w = blockIdx.x;
  int tid = threadIdx.x;
  int wl = w & 63;
  int b = wl & 15, hb = wl >> 4;
  int gate = tid >> 6, hl = tid & 63, hidx = hb*64 + hl;
  int j = gate*256 + hidx;
  __shared__ float4 hs4[64], ys4[64];
  __shared__ float gv[4][64];
  float* hs = (float*)hs4;
  float* ys = (float*)ys4;
  if (w < 64){
    if (p >= T_) return;
    int par = p & 1, npar = par ^ 1;
    hs[tid] = ws[WS_H0S + par*4096 + b*256 + tid];
    __syncthreads();
    float x = input_dec[p*16 + b];
    float a0 = fmaf(x, w_ih0[j], b_ih0[j] + b_hh0[j]);
    float a1 = 0.f, a2 = 0.f, a3 = 0.f;
    const float4* wr = (const float4*)(w_hh0 + j*256);
    #pragma unroll 8
    for (int k4 = 0; k4 < 64; ++k4){
      float4 wv = wr[k4];
      float4 hv = hs4[k4];
      a0 = fmaf(wv.x, hv.x, a0); a1 = fmaf(wv.y, hv.y, a1);
      a2 = fmaf(wv.z, hv.z, a2); a3 = fmaf(wv.w, hv.w, a3);
    }
    gv[gate][hl] = (a0 + a1) + (a2 + a3);
    __syncthreads();
    if (gate == 0){
      float ig = sigm(gv[0][hl]), fg = sigm(gv[1][hl]);
      float gg = tanhx(gv[2][hl]), og = sigm(gv[3][hl]);
      float cold = ws[WS_C0S + par*4096 + b*256 + hidx];
      float cn = fmaf(fg, cold, ig*gg);
      float hn = og * tanhx(cn);
      ws[WS_C0S + npar*4096 + b*256 + hidx] = cn;
      ws[WS_H0S + npar*4096 + b*256 + hidx] = hn;
      ws[WS_Y0 + (p*16 + b)*256 + hidx] = hn;
      if (p == T_-1){
        out[OUT_HID  + b*256 + hidx] = hn;
        out[OUT_CELL + b*256 + hidx] = cn;
      }
    }
  } else {
    int q = p - 1;
    if (q < 0) return;
    int par = q & 1, npar = par ^ 1;
    hs[tid] = ws[WS_H1S + par*4096 + b*256 + tid];
    ys[tid] = ws[WS_Y0 + (q*16 + b)*256 + tid];
    __syncthreads();
    float a0 = b_ih1[j] + b_hh1[j];
    float a1 = 0.f, a2 = 0.f, a3 = 0.f;
    const float4* wi = (const float4*)(w_ih1 + j*256);
    const float4* wh = (const float4*)(w_hh1 + j*256);
    #pragma unroll 4
    for (int k4 = 0; k4 < 64; ++k4){
      float4 wv = wi[k4], yv = ys4[k4];
      a0 = fmaf(wv.x, yv.x, a0); a1 = fmaf(wv.y, yv.y, a1);
      a2 = fmaf(wv.z, yv.z, a2); a3 = fmaf(wv.w, yv.w, a3);
      float4 wv2 = wh[k4], hv = hs4[k4];
      a0 = fmaf(wv2.x, hv.x, a0); a1 = fmaf(wv2.y, hv.y, a1);
      a2 = fmaf(wv2.z, hv.z, a2); a3 = fmaf(wv2.w, hv.w, a3);
    }
    gv[gate][hl] = (a0 + a1) + (a2 + a3);
    __syncthreads();
    if (gate == 0){
      float ig = sigm(gv[0][hl]), fg = sigm(gv[1][hl]);
      float gg = tanhx(gv[2][hl]), og = sigm(gv[3][hl]);
      float cold = ws[WS_C1S + par*4096 + b*256 + hidx];
      float cn = fmaf(fg, cold, ig*gg);
      float hn = og * tanhx(cn);
      ws[WS_C1S + npar*4096 + b*256 + hidx] = cn;
      ws[WS_H1S + npar*4096 + b*256 + hidx] = hn;
      ws[WS_OD + (q*16 + b)*256 + hidx] = hn;
      if (q == T_-1){
        out[OUT_HID  + 4096 + b*256 + hidx] = hn;
        out[OUT_CELL + 4096 + b*256 + hidx] = cn;
      }
    }
  }
}

// ---------------- odp2[t][b][a] = (od @ W_attn[:,512:768]^T) * 2log2e ----------------
__global__ __launch_bounds__(256) void k_odp(float* __restrict__ ws){
  int row = blockIdx.x;        // 512 = t*16+b
  int tid = threadIdx.x;
  __shared__ float odl[256];
  odl[tid] = ws[WS_OD + row*256 + tid];
  __syncthreads();
  if (tid < 100){
    float acc = 0.f;
    for (int k = 0; k < 256; ++k) acc = fmaf(ws[WS_WODT + k*100 + tid], odl[k], acc);
    ws[WS_ODP2 + row*100 + tid] = acc * L2E2;
  }
}

// ---------------- attention recurrence: 8 WGs per batch element, s-split ----------------
__global__ __launch_bounds__(512) void k_attn(const float* __restrict__ amask,
    const float* __restrict__ W_attn, const float* __restrict__ wout_g,
    float* __restrict__ out, float* __restrict__ ws){
  int wg = blockIdx.x;          // 128 = b*8 + sb
  int b = wg >> 3, sb = wg & 7;
  int s0 = sb*50;
  int tid = threadIdx.x;
  int oct = tid >> 6, sl = tid & 63;
  bool valid = sl < 50;
  __shared__ float cov[64], amL[64], eo[8][64], odp_l[100];
  __shared__ float2 wcwo[100];
  __shared__ float bcast[2];
  if (tid < 100){
    wcwo[tid] = make_float2(W_attn[tid*769 + 768] * L2E2, -2.f * wout_g[tid]);
  }
  if (tid == 0){
    float wsum = 0.f;
    for (int a2 = 0; a2 < 100; ++a2) wsum += wout_g[a2];
    bcast[1] = wsum;
  }
  if (tid < 64){
    cov[tid] = 0.f;
    amL[tid] = valid ? amask[(s0 + tid)*16 + b] * L2E : 0.f;
  }
  const float* bp = ws + WS_BASE2 + b*(A_*S_) + s0 + sl;
  int* flagp   = (int*)(ws + WS_FLAG) + b;
  float* esump = ws + WS_ESUM + b;
  __syncthreads();
  float woSum = bcast[1];
  for (int t = 0; t < T_; ++t){
    if (tid < 100) odp_l[tid] = ws[WS_ODP2 + (t*16 + b)*100 + tid];
    __syncthreads();
    float e = 0.f;
    if (valid){
      float cv = cov[sl];
      #pragma unroll 4
      for (int a = oct; a < 100; a += 8){
        float2 ww = wcwo[a];
        float x = fmaf(ww.x, cv, bp[a*400] + odp_l[a]);
        float r = frcp(1.f + fexp2(x));
        e = fmaf(ww.y, r, e);
      }
    }
    eo[oct][sl] = e;
    __syncthreads();
    float ex = 0.f;
    if (tid < 64){
      float et = woSum + ((eo[0][tid]+eo[1][tid])+(eo[2][tid]+eo[3][tid]))
                       + ((eo[4][tid]+eo[5][tid])+(eo[6][tid]+eo[7][tid]));
      ex = (tid < 50) ? fexp2(fmaf(et, L2E, amL[tid])) : 0.f;
      float p = ex;
      #pragma unroll
      for (int m = 32; m >= 1; m >>= 1) p += __shfl_xor(p, m);
      if (tid == 0){
        atomicAdd(esump + t*16, p);
        __hip_atomic_fetch_add(flagp + t*16, 1, __ATOMIC_RELEASE, __HIP_MEMORY_SCOPE_AGENT);
        while (__hip_atomic_load(flagp + t*16, __ATOMIC_ACQUIRE, __HIP_MEMORY_SCOPE_AGENT) < 8)
          __builtin_amdgcn_s_sleep(8);
        bcast[0] = __hip_atomic_load(esump + t*16, __ATOMIC_ACQUIRE, __HIP_MEMORY_SCOPE_AGENT);
      }
    }
    __syncthreads();
    if (tid < 64){
      float inv = frcp(bcast[0]);
      float at = ex * inv;
      float cvo = cov[tid];
      float cl = fminf(at, cvo);
      float p = cl;
      #pragma unroll
      for (int m = 32; m >= 1; m >>= 1) p += __shfl_xor(p, m);
      if (tid < 50){
        cov[tid] = cvo + at;
        ws[WS_ATTN + (b*400 + s0 + tid)*32 + t] = at;
      }
      if (tid == 0) atomicAdd(out + OUT_CL + t*16 + b, p);
    }
    __syncthreads();
  }
  if (tid < 50) out[OUT_COV + (s0 + tid)*16 + b] = cov[tid];
}

// ---------------- context partials: ctx[sh][t][b][j] = sum_{s in half} attn*enc ----------------
__global__ __launch_bounds__(256) void k_ctx(const float* __restrict__ enc,
    const float* __restrict__ attn, float* __restrict__ ctx){
  int b = blockIdx.x, jh = blockIdx.y, sh = blockIdx.z;   // (16,2,2)
  int j = jh*256 + threadIdx.x;
  float acc[32];
  #pragma unroll
  for (int t = 0; t < 32; ++t) acc[t] = 0.f;
  const float* ap0 = attn + b*400*32;
  for (int s = sh*200; s < sh*200 + 200; ++s){
    float evv = enc[(s*16 + b)*512 + j];
    const float* ap = ap0 + s*32;
    #pragma unroll
    for (int t = 0; t < 32; ++t) acc[t] = fmaf(ap[t], evv, acc[t]);
  }
  #pragma unroll
  for (int t = 0; t < 32; ++t) ctx[sh*262144 + (t*16 + b)*512 + j] = acc[t];
}

// ---------------- pgen + h1 (vocab hidden) per (t,b) ----------------
__global__ __launch_bounds__(256) void k_pgen_h1(const float* __restrict__ input_dec,
    const float* __restrict__ emb, const float* __restrict__ b_v1,
    const float* __restrict__ W_pgen, const float* __restrict__ b_pgen,
    float* __restrict__ ws){
  int row = blockIdx.x, tid = threadIdx.x;
  __shared__ float pv[768], el[50], red[16];
  pv[tid]       = ws[WS_OD + row*256 + tid];
  pv[256 + tid] = ws[WS_CTX + row*512 + tid]       + ws[WS_CTX + 262144 + row*512 + tid];
  pv[512 + tid] = ws[WS_CTX + row*512 + 256 + tid] + ws[WS_CTX + 262144 + row*512 + 256 + tid];
  int tok = (int)input_dec[row];
  if (tid < 50) el[tid] = emb[tok*50 + tid];
  __syncthreads();
  float p = 0.f;
  for (int k = tid; k < 818; k += 256){
    float x = (k < 512) ? pv[256 + k] : (k < 768) ? pv[k - 512] : el[k - 768];
    p = fmaf(W_pgen[k], x, p);
  }
  p = bredSum(p, red);
  if (tid == 0) ws[WS_PGEN + row] = sigm(p + b_pgen[0]);
  if (tid < 100){
    float acc = b_v1[tid];
    for (int k = 0; k < 768; ++k) acc = fmaf(ws[WS_WV1T + k*100 + tid], pv[k], acc);
    ws[WS_H1V + row*100 + tid] = acc;
  }
}

// ---------------- logits = h1 @ W_v2^T + b_v2, + per-row exp-sum accumulation ----------------
__global__ __launch_bounds__(256) void k_logits(const float* __restrict__ W_v2,
    const float* __restrict__ b_v2, float* __restrict__ ws, float* __restrict__ out){
  int chunk = blockIdx.x, rblk = blockIdx.y;   // (391, 8)
  int vbase = chunk*128, rbase = rblk*64;
  __shared__ float h1l[100][68];
  __shared__ float wl[100][132];
  int tid = threadIdx.x;
  for (int o = tid; o < 6400; o += 256){
    int r = o/100, f = o%100;
    h1l[f][r] = ws[WS_H1V + (rbase + r)*100 + f];
  }
  for (int o = tid; o < 12800; o += 256){
    int vl = o/100, f = o%100;
    int v = vbase + vl;
    wl[f][vl] = (v < V_) ? W_v2[v*100 + f] : 0.f;
  }
  __syncthreads();
  int vb = (tid & 15)*8, rb = (tid >> 4)*4;
  float acc[4][8];
  #pragma unroll
  for (int i = 0; i < 4; ++i)
    #pragma unroll
    for (int jj = 0; jj < 8; ++jj) acc[i][jj] = 0.f;
  for (int f = 0; f < 100; ++f){
    float4 h4 = *(const float4*)&h1l[f][rb];
    float4 w0 = *(const float4*)&wl[f][vb];
    float4 w1 = *(const float4*)&wl[f][vb+4];
    float hv[4] = {h4.x, h4.y, h4.z, h4.w};
    float wv[8] = {w0.x, w0.y, w0.z, w0.w, w1.x, w1.y, w1.z, w1.w};
    #pragma unroll
    for (int i = 0; i < 4; ++i)
      #pragma unroll
      for (int jj = 0; jj < 8; ++jj) acc[i][jj] = fmaf(hv[i], wv[jj], acc[i][jj]);
  }
  float bv[8];
  #pragma unroll
  for (int jj = 0; jj < 8; ++jj){
    int v = vbase + vb + jj;
    bv[jj] = (v < V_) ? b_v2[v] : 0.f;
  }
  float ps[4] = {0.f, 0.f, 0.f, 0.f};
  #pragma unroll
  for (int i = 0; i < 4; ++i){
    int row = rbase + rb + i;
    int base = row*BV_ + vbase + vb;
    if (chunk < 390){
      #pragma unroll
      for (int jj = 0; jj < 8; ++jj){
        float val = acc[i][jj] + bv[jj];
        out[base + jj] = val;
        ps[i] += fexp2(val * L2E);
      }
    } else {
      for (int jj = 0; jj < 8; ++jj){
        int v = vbase + vb + jj;
        if (v < V_){
          float val = acc[i][jj] + bv[jj];
          out[row*BV_ + v] = val;
          ps[i] += fexp2(val * L2E);
        }
      }
    }
  }
  // reduce across the 16 lanes sharing this row group
  #pragma unroll
  for (int m = 1; m <= 8; m <<= 1){
    #pragma unroll
    for (int i = 0; i < 4; ++i) ps[i] += __shfl_xor(ps[i], m);
  }
  if ((tid & 15) == 0){
    #pragma unroll
    for (int i = 0; i < 4; ++i) atomicAdd(ws + WS_VSUM + rbase + rb + i, ps[i]);
  }
}

// ---------------- in-place softmax * pgen + zero pad ----------------
__global__ __launch_bounds__(256) void k_finalize(float* __restrict__ out, const float* __restrict__ ws){
  int row = blockIdx.y;
  float sc = ws[WS_PGEN + row] / ws[WS_VSUM + row];
  int v4 = (blockIdx.x*256 + threadIdx.x)*4;
  if (v4 < V_){
    float2* p0 = (float2*)&out[row*BV_ + v4];
    float2 a = p0[0], b2 = p0[1];
    a.x  = fexp2(a.x  * L2E)*sc;
    a.y  = fexp2(a.y  * L2E)*sc;
    b2.x = fexp2(b2.x * L2E)*sc;
    b2.y = fexp2(b2.y * L2E)*sc;
    p0[0] = a; p0[1] = b2;
  }
  if (blockIdx.x == 49 && threadIdx.x < 50) out[row*BV_ + V_ + threadIdx.x] = 0.f;
}

// ---------------- copy-distribution scatter ----------------
__global__ __launch_bounds__(256) void k_scatter(const int* __restrict__ real_index,
    const float* __restrict__ ws, float* __restrict__ out){
  int i = blockIdx.x*256 + threadIdx.x;   // < 16*400*32
  int b = i / 12800, r = i % 12800, s = r >> 5, t = r & 31;
  float at = ws[WS_ATTN + i];
  float w = 1.f - ws[WS_PGEN + t*16 + b];
  int col = real_index[s*16 + b];
  atomicAdd(out + (t*16 + b)*BV_ + col, at*w);
}

extern "C" void kernel_launch(void* const* d_in, const int* in_sizes, int n_in,
                              void* d_out, int out_size, void* d_ws, size_t ws_size,
                              hipStream_t stream){
  const float* output_enc = (const float*)d_in[0];
  const int*   real_index = (const int*)d_in[1];
  const float* input_dec  = (const float*)d_in[3];
  const float* hidden_enc = (const float*)d_in[4];
  const float* cell_enc   = (const float*)d_in[5];
  const float* att_mask   = (const float*)d_in[6];
  const float* emb        = (const float*)d_in[7];
  const float* W_reduce   = (const float*)d_in[8];
  const float* b_reduce   = (const float*)d_in[9];
  const float* w_ih0      = (const float*)d_in[10];
  const float* w_hh0      = (const float*)d_in[11];
  const float* b_ih0      = (const float*)d_in[12];
  const float* b_hh0      = (const float*)d_in[13];
  const float* w_ih1      = (const float*)d_in[14];
  const float* w_hh1      = (const float*)d_in[15];
  const float* b_ih1      = (const float*)d_in[16];
  const float* b_hh1      = (const float*)d_in[17];
  const float* W_attn     = (const float*)d_in[18];
  const float* b_attn     = (const float*)d_in[19];
  const float* w_attn_out = (const float*)d_in[20];
  const float* W_v1       = (const float*)d_in[21];
  const float* b_v1       = (const float*)d_in[22];
  const float* W_v2       = (const float*)d_in[23];
  const float* b_v2       = (const float*)d_in[24];
  const float* W_pgen     = (const float*)d_in[25];
  const float* b_pgen     = (const float*)d_in[26];
  float* out = (float*)d_out;
  float* ws  = (float*)d_ws;
  if (ws_size < (size_t)WS_TOTAL * sizeof(float)) return;

  k_prep<<<dim3(920), dim3(256), 0, stream>>>(W_attn, W_v1, W_reduce, out, ws);
  k_reduce_enc<<<dim3(32), dim3(256), 0, stream>>>(hidden_enc, cell_enc, b_reduce, ws);
  k_enc_base<<<dim3(25, 2, 16), dim3(256), 0, stream>>>(output_enc, W_attn, b_attn, ws);
  for (int p = 0; p <= T_; ++p)
    k_lstm<<<dim3(128), dim3(256), 0, stream>>>(input_dec, w_ih0, w_hh0, b_ih0, b_hh0,
                                                w_ih1, w_hh1, b_ih1, b_hh1, ws, out, p);
  k_odp<<<dim3(512), dim3(256), 0, stream>>>(ws);
  k_attn<<<dim3(128), dim3(512), 0, stream>>>(att_mask, W_attn, w_attn_out, out, ws);
  k_ctx<<<dim3(16, 2, 2), dim3(256), 0, stream>>>(output_enc, ws + WS_ATTN, ws + WS_CTX);
  k_pgen_h1<<<dim3(512), dim3(256), 0, stream>>>(input_dec, emb, b_v1, W_pgen, b_pgen, ws);
  k_logits<<<dim3(391, 8), dim3(256), 0, stream>>>(W_v2, b_v2, ws, out);
  k_finalize<<<dim3(50, 512), dim3(256), 0, stream>>>(out, ws);
  k_scatter<<<dim3(800), dim3(256), 0, stream>>>(real_index, ws, out);
}

// Round 3
// 1180.427 us; speedup vs baseline: 1.2329x; 1.1010x over previous
//
#include <hip/hip_runtime.h>
#include <math.h>

#define S_   400
#define B_   16
#define T_   32
#define H_   256
#define A_   100
#define G_   50
#define VF_  100
#define V_   50000
#define BV_  50050

#define L2E   1.44269504088896f
#define L2E2  2.88539008177793f

// ---- ws offsets (floats) ----
#define WS_H0S   0          // [2][256][16] h-major state, parity buffered
#define WS_C0S   8192
#define WS_H1S   16384
#define WS_C1S   24576
#define WS_Y0    32768      // [32][256][16] layer0 outputs (h-major)
#define WS_OD    163840     // [32][256][16] layer1 outputs (h-major)
#define WS_WT0   294912     // [256][1024] permuted k-major w_hh0
#define WS_WTI1  557056     // [256][1024] permuted k-major w_ih1
#define WS_WTH1  819200     // [256][1024] permuted k-major w_hh1
#define WS_WODT  1081344    // [256][100]  W_attn[:,512:768]^T
#define WS_WV1T  1106944    // [768][100]  W_v1^T
#define WS_WRT   1183744    // [512][256]  W_reduce^T
#define WS_BASE2 1314816    // [16][100][400]  (enc@Wattn + b_attn)*2log2e
#define WS_ODP2  1954816    // [32*16][100]
#define WS_ATTN  2006016    // [16][32][400]
#define WS_H1V   2210816    // [512][100]
#define WS_PGEN  2262016    // [512]
#define WS_VSUM  2262528    // [512]
#define WS_TOTAL 2263040

// ---- out offsets (floats) ----
#define OUT_CL   25625600
#define OUT_COV  25626112
#define OUT_HID  25632512
#define OUT_CELL 25640704
// first 8*512*512 floats of out are used as ctx-partial scratch (overwritten by k_logits later)
#define CTXP_SZ  262144

__device__ __forceinline__ float fexp2(float x){ return __builtin_amdgcn_exp2f(x); }
__device__ __forceinline__ float frcp (float x){ return __builtin_amdgcn_rcpf(x); }
__device__ __forceinline__ float sigm (float x){ return frcp(1.f + fexp2(-L2E*x)); }
__device__ __forceinline__ float tanhx(float x){ return fmaf(-2.f, frcp(1.f + fexp2(L2E2*x)), 1.f); }

__device__ __forceinline__ float bredSum(float v, float* red){
  #pragma unroll
  for (int m = 32; m >= 1; m >>= 1) v += __shfl_xor(v, m);
  __syncthreads();
  if ((threadIdx.x & 63) == 0) red[threadIdx.x >> 6] = v;
  __syncthreads();
  float r = 0.f;
  int nw = blockDim.x >> 6;
  for (int k = 0; k < nw; ++k) r += red[k];
  return r;
}

// ---------------- prep: tiled permuted transposes + small transposes + zero ----------------
__global__ __launch_bounds__(256) void k_prep(const float* __restrict__ w_hh0,
    const float* __restrict__ w_ih1, const float* __restrict__ w_hh1,
    const float* __restrict__ W_attn, const float* __restrict__ W_v1,
    const float* __restrict__ W_reduce, float* __restrict__ ws){
  int bx = blockIdx.x, tid = threadIdx.x;
  __shared__ float tile[64*65];
  if (bx < 192){
    int m = bx >> 6, t6 = bx & 63;
    int kb = t6 & 3, cb = t6 >> 2;
    const float* src = (m == 0) ? w_hh0 : (m == 1) ? w_ih1 : w_hh1;
    int dstoff = (m == 0) ? WS_WT0 : (m == 1) ? WS_WTI1 : WS_WTH1;
    for (int o = tid; o < 4096; o += 256){
      int cc = o >> 6, kk = o & 63;
      int c = cb*64 + cc;
      int j;
      if (m == 0){ int w = c >> 6, l = c & 63; j = (l>>4)*256 + w*16 + (l&15); }
      else       { int u = c >> 5, idx = c & 31; j = (idx>>3)*256 + u*8 + (idx&7); }
      tile[cc*65 + kk] = src[j*256 + kb*64 + kk];
    }
    __syncthreads();
    for (int o = tid; o < 4096; o += 256){
      int kk = o >> 6, cc = o & 63;
      ws[dstoff + (kb*64 + kk)*1024 + cb*64 + cc] = tile[cc*65 + kk];
    }
    return;
  }
  if (bx < 224){
    int t6 = bx - 192;      // W_reduce [256 j][512 k] -> WRT [512 k][256 j]
    int kb = t6 & 7, jb = t6 >> 3;
    for (int o = tid; o < 4096; o += 256){
      int jj = o >> 6, kk = o & 63;
      tile[jj*65 + kk] = W_reduce[(jb*64 + jj)*512 + kb*64 + kk];
    }
    __syncthreads();
    for (int o = tid; o < 4096; o += 256){
      int kk = o >> 6, jj = o & 63;
      ws[WS_WRT + (kb*64 + kk)*256 + jb*64 + jj] = tile[jj*65 + kk];
    }
    return;
  }
  int i = (bx - 224)*256 + tid;
  if (i < 25600){ int k = i/100, a = i%100; ws[WS_WODT + i] = W_attn[a*769 + 512 + k]; return; }
  i -= 25600;
  if (i < 76800){ int k = i/100, f = i%100; ws[WS_WV1T + i] = W_v1[f*768 + k]; return; }
  i -= 76800;
  if (i < 512){ ws[WS_VSUM + i] = 0.f; return; }
}

// ---------------- encoder state reduce (writes h-major state) ----------------
__global__ __launch_bounds__(256) void k_reduce_enc(const float* __restrict__ he,
    const float* __restrict__ ce, const float* __restrict__ b_reduce, float* __restrict__ ws){
  int bx = blockIdx.x;            // 32 blocks: l = bx>>4, b = bx&15
  int l = bx >> 4, b = bx & 15, j = threadIdx.x;
  const float* wrt = ws + WS_WRT;
  const float* h_a = he + (l*B_ + b)*H_;
  const float* h_b = he + ((l+2)*B_ + b)*H_;
  const float* c_a = ce + (l*B_ + b)*H_;
  const float* c_b = ce + ((l+2)*B_ + b)*H_;
  float ah = b_reduce[j], ac = b_reduce[j];
  for (int k = 0; k < 256; ++k){
    float w0 = wrt[k*256 + j];
    float w1 = wrt[(256+k)*256 + j];
    ah += w0*h_a[k] + w1*h_b[k];
    ac += w0*c_a[k] + w1*c_b[k];
  }
  if (l == 0){ ws[WS_H0S + j*16 + b] = ah; ws[WS_C0S + j*16 + b] = ac; }
  else       { ws[WS_H1S + j*16 + b] = ah; ws[WS_C1S + j*16 + b] = ac; }
}

// ---------------- enc_base = (output_enc @ W_attn[:, :512]^T + b_attn)*2log2e ----------------
__global__ __launch_bounds__(256) void k_enc_base(const float* __restrict__ enc,
    const float* __restrict__ W_attn, const float* __restrict__ b_attn, float* __restrict__ ws){
  int st = blockIdx.x, ah = blockIdx.y, b = blockIdx.z;   // (25, 2, 16)
  int s_base = st*16;
  __shared__ float encs[16][132];
  __shared__ float was[50][132];
  int tid = threadIdx.x;
  bool act = tid < 200;
  int sg = tid & 7, ag = tid >> 3;
  int sl = sg*2, al = ag*2;
  float acc00=0.f, acc01=0.f, acc10=0.f, acc11=0.f;
  for (int kc = 0; kc < 4; ++kc){
    int k0 = kc*128;
    __syncthreads();
    for (int o = tid; o < 512; o += 256){
      int r = o >> 5, c4 = (o & 31)*4;
      float4 v = *(const float4*)(enc + ((s_base + r)*B_ + b)*512 + k0 + c4);
      *(float4*)&encs[r][c4] = v;
    }
    for (int o = tid; o < 6400; o += 256){
      int r = o >> 7, c = o & 127;
      was[r][c] = W_attn[(ah*50 + r)*769 + k0 + c];
    }
    __syncthreads();
    if (act){
      for (int k = 0; k < 128; ++k){
        float e0 = encs[sl][k], e1 = encs[sl+1][k];
        float w0 = was[al][k],  w1 = was[al+1][k];
        acc00 = fmaf(e0, w0, acc00); acc01 = fmaf(e0, w1, acc01);
        acc10 = fmaf(e1, w0, acc10); acc11 = fmaf(e1, w1, acc11);
      }
    }
  }
  if (act){
    int a = ah*50 + al, s = s_base + sl;
    float* bpp = ws + WS_BASE2 + (b*A_)*S_;
    bpp[(a  )*S_ + s  ] = (acc00 + b_attn[a  ]) * L2E2;
    bpp[(a+1)*S_ + s  ] = (acc01 + b_attn[a+1]) * L2E2;
    bpp[(a  )*S_ + s+1] = (acc10 + b_attn[a  ]) * L2E2;
    bpp[(a+1)*S_ + s+1] = (acc11 + b_attn[a+1]) * L2E2;
  }
}

// ---------------- LSTM phase p: WGs 0-15 layer0 step p, WGs 16-47 layer1 step p-1 ----------------
__global__ __launch_bounds__(256) void k_lstm2(const float* __restrict__ input_dec,
    const float* __restrict__ w_ih0, const float* __restrict__ b_ih0, const float* __restrict__ b_hh0,
    const float* __restrict__ b_ih1, const float* __restrict__ b_hh1,
    float* __restrict__ ws, float* __restrict__ out, int p){
  int wgs = blockIdx.x;
  int tid = threadIdx.x;
  __shared__ float hs[4096];
  __shared__ float ys[4096];
  __shared__ float gv[1088];
  __shared__ float xs[16];
  if (wgs < 16){
    if (p >= T_) return;
    int w = wgs;
    int par = p & 1, npar = par ^ 1;
    for (int o = tid; o < 4096; o += 256) hs[o] = ws[WS_H0S + par*4096 + o];
    if (tid < 16) xs[tid] = input_dec[p*16 + tid];
    __syncthreads();
    int bg = tid >> 6, l = tid & 63;
    int g = l >> 4, hh = l & 15;
    int j = g*256 + w*16 + hh;
    float bias = b_ih0[j] + b_hh0[j];
    float wih = w_ih0[j];
    float x0 = xs[bg*4+0], x1 = xs[bg*4+1], x2 = xs[bg*4+2], x3 = xs[bg*4+3];
    float a0 = fmaf(x0, wih, bias);
    float a1 = fmaf(x1, wih, bias);
    float a2 = fmaf(x2, wih, bias);
    float a3 = fmaf(x3, wih, bias);
    const float* wp = ws + WS_WT0 + w*64 + l;
    #pragma unroll 8
    for (int k = 0; k < 256; ++k){
      float wv = wp[k*1024];
      float4 hv = *(const float4*)&hs[k*16 + bg*4];
      a0 = fmaf(wv, hv.x, a0); a1 = fmaf(wv, hv.y, a1);
      a2 = fmaf(wv, hv.z, a2); a3 = fmaf(wv, hv.w, a3);
    }
    int gb = (g*16 + hh)*17 + bg*4;
    gv[gb+0] = a0; gv[gb+1] = a1; gv[gb+2] = a2; gv[gb+3] = a3;
    __syncthreads();
    int b = tid & 15, h2 = tid >> 4;
    float gi = gv[(0*16+h2)*17 + b], gf = gv[(1*16+h2)*17 + b];
    float gg = gv[(2*16+h2)*17 + b], go = gv[(3*16+h2)*17 + b];
    int hidx = w*16 + h2;
    float cold = ws[WS_C0S + par*4096 + hidx*16 + b];
    float ig = sigm(gi), fg = sigm(gf), gt = tanhx(gg), og = sigm(go);
    float cn = fmaf(fg, cold, ig*gt);
    float hn = og * tanhx(cn);
    ws[WS_C0S + npar*4096 + hidx*16 + b] = cn;
    ws[WS_H0S + npar*4096 + hidx*16 + b] = hn;
    ws[WS_Y0 + p*4096 + hidx*16 + b] = hn;
    if (p == T_-1){
      out[OUT_HID  + b*256 + hidx] = hn;
      out[OUT_CELL + b*256 + hidx] = cn;
    }
  } else {
    int q = p - 1;
    if (q < 0) return;
    int u = wgs - 16;
    int par = q & 1, npar = par ^ 1;
    for (int o = tid; o < 4096; o += 256){
      ys[o] = ws[WS_Y0 + q*4096 + o];
      hs[o] = ws[WS_H1S + par*4096 + o];
    }
    __syncthreads();
    int bg = tid >> 5, idx = tid & 31;
    int g = idx >> 3, hh = idx & 7;
    int j = g*256 + u*8 + hh;
    float bias = b_ih1[j] + b_hh1[j];
    float ai0 = bias, ah0 = 0.f, ai1 = bias, ah1 = 0.f;
    const float* wip = ws + WS_WTI1 + u*32 + idx;
    const float* whp = ws + WS_WTH1 + u*32 + idx;
    #pragma unroll 8
    for (int k = 0; k < 256; ++k){
      float wi = wip[k*1024];
      float wh = whp[k*1024];
      float2 yv = *(const float2*)&ys[k*16 + bg*2];
      float2 hv = *(const float2*)&hs[k*16 + bg*2];
      ai0 = fmaf(wi, yv.x, ai0); ai1 = fmaf(wi, yv.y, ai1);
      ah0 = fmaf(wh, hv.x, ah0); ah1 = fmaf(wh, hv.y, ah1);
    }
    int gb = g*136 + hh*17 + bg*2;
    gv[gb+0] = ai0 + ah0; gv[gb+1] = ai1 + ah1;
    __syncthreads();
    if (tid < 128){
      int b = tid & 15, h2 = (tid >> 4) & 7;
      float gi = gv[0*136 + h2*17 + b], gf = gv[1*136 + h2*17 + b];
      float gg = gv[2*136 + h2*17 + b], go = gv[3*136 + h2*17 + b];
      int hidx = u*8 + h2;
      float cold = ws[WS_C1S + par*4096 + hidx*16 + b];
      float ig = sigm(gi), fg = sigm(gf), gt = tanhx(gg), og = sigm(go);
      float cn = fmaf(fg, cold, ig*gt);
      float hn = og * tanhx(cn);
      ws[WS_C1S + npar*4096 + hidx*16 + b] = cn;
      ws[WS_H1S + npar*4096 + hidx*16 + b] = hn;
      ws[WS_OD + q*4096 + hidx*16 + b] = hn;
      if (q == T_-1){
        out[OUT_HID  + 4096 + b*256 + hidx] = hn;
        out[OUT_CELL + 4096 + b*256 + hidx] = cn;
      }
    }
  }
}

// ---------------- odp2[t*16+b][a] = (od @ W_attn[:,512:768]^T) * 2log2e ----------------
__global__ __launch_bounds__(256) void k_odp(float* __restrict__ ws){
  int row = blockIdx.x;        // 512 = t*16+b
  int t = row >> 4, b = row & 15;
  int tid = threadIdx.x;
  __shared__ float odl[256];
  odl[tid] = ws[WS_OD + t*4096 + tid*16 + b];
  __syncthreads();
  if (tid < 100){
    float acc = 0.f;
    for (int k = 0; k < 256; ++k) acc = fmaf(ws[WS_WODT + k*100 + tid], odl[k], acc);
    ws[WS_ODP2 + row*100 + tid] = acc * L2E2;
  }
}

// ---------------- attention recurrence: one WG per batch, base2 in registers ----------------
__global__ __launch_bounds__(1024) void k_attn(const float* __restrict__ amask,
    const float* __restrict__ W_attn, const float* __restrict__ wout_g,
    float* __restrict__ out, float* __restrict__ ws){
  int b = blockIdx.x;
  int tid = threadIdx.x;
  int wv = tid >> 6, l = tid & 63;
  int half = wv & 1, sblk = wv >> 1;
  int s = sblk*64 + l;
  bool cvalid = (sblk < 7) && (s < 400);
  int a0 = half*50;
  __shared__ float cov[400], eh[2][400], amL[400], red[2][8];
  __shared__ float4 f4[100];
  __shared__ float wcwo[200];
  if (tid < 100){
    wcwo[tid]       = W_attn[tid*769 + 768] * L2E2;
    wcwo[100 + tid] = -2.f * wout_g[tid];
  }
  if (tid < 400){ cov[tid] = 0.f; amL[tid] = amask[tid*16 + b] * L2E; }
  __syncthreads();
  float woSum = 0.f;
  for (int a = 0; a < 100; ++a) woSum -= 0.5f * wcwo[100 + a];
  float ba[50];
  #pragma unroll
  for (int i = 0; i < 50; ++i)
    ba[i] = cvalid ? ws[WS_BASE2 + (b*100 + a0 + i)*400 + s] : 0.f;

  for (int t = 0; t < T_; ++t){
    if (tid < 100){
      float od = ws[WS_ODP2 + (t*16 + b)*100 + tid];
      f4[tid] = make_float4(od, wcwo[tid], wcwo[100 + tid], 0.f);
    }
    __syncthreads();     // S1: f4 ready, cov stable
    float ep = 0.f;
    if (cvalid){
      float cv = cov[s];
      #pragma unroll
      for (int i = 0; i < 50; ++i){
        float4 q = f4[a0 + i];
        float x = fmaf(q.y, cv, ba[i] + q.x);
        ep = fmaf(q.z, frcp(1.f + fexp2(x)), ep);
      }
      eh[half][s] = ep;
    }
    __syncthreads();     // S2
    float ex = 0.f;
    if (tid < 400){
      float et = woSum + eh[0][tid] + eh[1][tid];
      ex = fexp2(fmaf(et, L2E, amL[tid]));
    }
    float ps = ex;
    #pragma unroll
    for (int m = 32; m >= 1; m >>= 1) ps += __shfl_xor(ps, m);
    if (l == 0 && wv < 7) red[0][wv] = ps;
    __syncthreads();     // S3
    float den = ((red[0][0]+red[0][1])+(red[0][2]+red[0][3]))
              + ((red[0][4]+red[0][5])+red[0][6]);
    float inv = frcp(den);
    float at = ex * inv;
    float cl = 0.f;
    if (tid < 400){
      float cvo = cov[tid];
      cl = fminf(at, cvo);
      cov[tid] = cvo + at;
      ws[WS_ATTN + (b*32 + t)*400 + tid] = at;
    }
    float p2 = cl;
    #pragma unroll
    for (int m = 32; m >= 1; m >>= 1) p2 += __shfl_xor(p2, m);
    if (l == 0 && wv < 7) red[1][wv] = p2;
    __syncthreads();     // S4
    if (tid == 0){
      float cls = ((red[1][0]+red[1][1])+(red[1][2]+red[1][3]))
                + ((red[1][4]+red[1][5])+red[1][6]);
      out[OUT_CL + t*16 + b] = cls;
    }
  }
  if (tid < 400) out[OUT_COV + tid*16 + b] = cov[tid];
}

// ---------------- context partials into out-scratch: ctxp[sc][t*16+b][512] ----------------
__global__ __launch_bounds__(256) void k_ctx(const float* __restrict__ enc,
    const float* __restrict__ ws, float* __restrict__ ctxp){
  int b = blockIdx.x, jh = blockIdx.y, sc = blockIdx.z;   // (16,2,8)
  int tid = threadIdx.x;
  __shared__ float at[32*52];
  for (int o = tid; o < 1600; o += 256){
    int t = o/50, s2 = o%50;
    at[t*52 + s2] = ws[WS_ATTN + (b*32 + t)*400 + sc*50 + s2];
  }
  __syncthreads();
  int j = jh*256 + tid;
  float acc[32];
  #pragma unroll
  for (int t = 0; t < 32; ++t) acc[t] = 0.f;
  for (int s2 = 0; s2 < 50; ++s2){
    float evv = enc[((sc*50 + s2)*16 + b)*512 + j];
    #pragma unroll
    for (int t = 0; t < 32; ++t) acc[t] = fmaf(at[t*52 + s2], evv, acc[t]);
  }
  #pragma unroll
  for (int t = 0; t < 32; ++t)
    ctxp[sc*CTXP_SZ + (t*16 + b)*512 + j] = acc[t];
}

// ---------------- pgen + h1 (vocab hidden) per (t,b) ----------------
__global__ __launch_bounds__(256) void k_pgen_h1(const float* __restrict__ input_dec,
    const float* __restrict__ emb, const float* __restrict__ b_v1,
    const float* __restrict__ W_pgen, const float* __restrict__ b_pgen,
    const float* __restrict__ ctxp, float* __restrict__ ws){
  int row = blockIdx.x, tid = threadIdx.x;
  int t = row >> 4, b = row & 15;
  __shared__ float pv[768], el[50], red[16];
  pv[tid] = ws[WS_OD + t*4096 + tid*16 + b];
  float c0 = 0.f, c1 = 0.f;
  #pragma unroll
  for (int sc = 0; sc < 8; ++sc){
    c0 += ctxp[sc*CTXP_SZ + row*512 + tid];
    c1 += ctxp[sc*CTXP_SZ + row*512 + 256 + tid];
  }
  pv[256 + tid] = c0;
  pv[512 + tid] = c1;
  int tok = (int)input_dec[row];
  if (tid < 50) el[tid] = emb[tok*50 + tid];
  __syncthreads();
  float p = 0.f;
  for (int k = tid; k < 818; k += 256){
    float x = (k < 512) ? pv[256 + k] : (k < 768) ? pv[k - 512] : el[k - 768];
    p = fmaf(W_pgen[k], x, p);
  }
  p = bredSum(p, red);
  if (tid == 0) ws[WS_PGEN + row] = sigm(p + b_pgen[0]);
  if (tid < 100){
    float acc = b_v1[tid];
    for (int k = 0; k < 768; ++k) acc = fmaf(ws[WS_WV1T + k*100 + tid], pv[k], acc);
    ws[WS_H1V + row*100 + tid] = acc;
  }
}

// ---------------- logits = h1 @ W_v2^T + b_v2 (64x64 tiles) + exp-sum ----------------
__global__ __launch_bounds__(256) void k_logits(const float* __restrict__ W_v2,
    const float* __restrict__ b_v2, float* __restrict__ ws, float* __restrict__ out){
  int vbase = blockIdx.x*64, rbase = blockIdx.y*64;   // (782, 8)
  int tid = threadIdx.x;
  __shared__ float wl[100*68];
  __shared__ float h1l[100*68];
  for (int o = tid; o < 6400; o += 256){
    int vl = o/100, f = o%100;
    int v = vbase + vl;
    wl[f*68 + vl] = (v < V_) ? W_v2[v*100 + f] : 0.f;
  }
  for (int o = tid; o < 6400; o += 256){
    int r = o/100, f = o%100;
    h1l[f*68 + r] = ws[WS_H1V + (rbase + r)*100 + f];
  }
  __syncthreads();
  int vg = tid & 15, rg = tid >> 4;
  float acc[4][4];
  #pragma unroll
  for (int i = 0; i < 4; ++i)
    #pragma unroll
    for (int jj = 0; jj < 4; ++jj) acc[i][jj] = 0.f;
  #pragma unroll 4
  for (int f = 0; f < 100; ++f){
    float4 wv4 = *(const float4*)&wl[f*68 + vg*4];
    float4 hv4 = *(const float4*)&h1l[f*68 + rg*4];
    float wvv[4] = {wv4.x, wv4.y, wv4.z, wv4.w};
    float hvv[4] = {hv4.x, hv4.y, hv4.z, hv4.w};
    #pragma unroll
    for (int i = 0; i < 4; ++i)
      #pragma unroll
      for (int jj = 0; jj < 4; ++jj) acc[i][jj] = fmaf(hvv[i], wvv[jj], acc[i][jj]);
  }
  int v0 = vbase + vg*4;
  bool fullv = (v0 + 3) < V_;
  float bv[4];
  #pragma unroll
  for (int jj = 0; jj < 4; ++jj)
    bv[jj] = (v0 + jj < V_) ? b_v2[v0 + jj] : 0.f;
  float ps[4];
  #pragma unroll
  for (int i = 0; i < 4; ++i){
    int row = rbase + rg*4 + i;
    float r0 = acc[i][0] + bv[0], r1 = acc[i][1] + bv[1];
    float r2 = acc[i][2] + bv[2], r3 = acc[i][3] + bv[3];
    if (fullv){
      float4 st = make_float4(r0, r1, r2, r3);
      *(float4*)&out[(size_t)row*BV_ + v0] = st;
      ps[i] = (fexp2(r0*L2E) + fexp2(r1*L2E)) + (fexp2(r2*L2E) + fexp2(r3*L2E));
    } else {
      float rr[4] = {r0, r1, r2, r3};
      ps[i] = 0.f;
      for (int jj = 0; jj < 4; ++jj){
        if (v0 + jj < V_){
          out[(size_t)row*BV_ + v0 + jj] = rr[jj];
          ps[i] += fexp2(rr[jj]*L2E);
        }
      }
    }
  }
  #pragma unroll
  for (int m = 1; m <= 8; m <<= 1){
    #pragma unroll
    for (int i = 0; i < 4; ++i) ps[i] += __shfl_xor(ps[i], m);
  }
  if (vg == 0){
    #pragma unroll
    for (int i = 0; i < 4; ++i) atomicAdd(ws + WS_VSUM + rbase + rg*4 + i, ps[i]);
  }
}

// ---------------- in-place softmax * pgen + zero pad ----------------
__global__ __launch_bounds__(256) void k_finalize(float* __restrict__ out, const float* __restrict__ ws){
  int row = blockIdx.y;
  float sc = ws[WS_PGEN + row] / ws[WS_VSUM + row];
  int v4 = (blockIdx.x*256 + threadIdx.x)*4;
  if (v4 < V_){
    float2* p0 = (float2*)&out[(size_t)row*BV_ + v4];
    float2 a = p0[0], b2 = p0[1];
    a.x  = fexp2(a.x  * L2E)*sc;
    a.y  = fexp2(a.y  * L2E)*sc;
    b2.x = fexp2(b2.x * L2E)*sc;
    b2.y = fexp2(b2.y * L2E)*sc;
    p0[0] = a; p0[1] = b2;
  }
  if (blockIdx.x == 49 && threadIdx.x < 50) out[(size_t)row*BV_ + V_ + threadIdx.x] = 0.f;
}

// ---------------- copy-distribution scatter ----------------
__global__ __launch_bounds__(256) void k_scatter(const int* __restrict__ real_index,
    const float* __restrict__ ws, float* __restrict__ out){
  int i = blockIdx.x*256 + threadIdx.x;   // 16*32*400
  int b = i / 12800, r = i % 12800, t = r / 400, s = r % 400;
  float at = ws[WS_ATTN + i];
  float w = 1.f - ws[WS_PGEN + t*16 + b];
  int col = real_index[s*16 + b];
  atomicAdd(out + (size_t)(t*16 + b)*BV_ + col, at*w);
}

extern "C" void kernel_launch(void* const* d_in, const int* in_sizes, int n_in,
                              void* d_out, int out_size, void* d_ws, size_t ws_size,
                              hipStream_t stream){
  const float* output_enc = (const float*)d_in[0];
  const int*   real_index = (const int*)d_in[1];
  const float* input_dec  = (const float*)d_in[3];
  const float* hidden_enc = (const float*)d_in[4];
  const float* cell_enc   = (const float*)d_in[5];
  const float* att_mask   = (const float*)d_in[6];
  const float* emb        = (const float*)d_in[7];
  const float* W_reduce   = (const float*)d_in[8];
  const float* b_reduce   = (const float*)d_in[9];
  const float* w_ih0      = (const float*)d_in[10];
  const float* w_hh0      = (const float*)d_in[11];
  const float* b_ih0      = (const float*)d_in[12];
  const float* b_hh0      = (const float*)d_in[13];
  const float* w_ih1      = (const float*)d_in[14];
  const float* w_hh1      = (const float*)d_in[15];
  const float* b_ih1      = (const float*)d_in[16];
  const float* b_hh1      = (const float*)d_in[17];
  const float* W_attn     = (const float*)d_in[18];
  const float* b_attn     = (const float*)d_in[19];
  const float* w_attn_out = (const float*)d_in[20];
  const float* W_v1       = (const float*)d_in[21];
  const float* b_v1       = (const float*)d_in[22];
  const float* W_v2       = (const float*)d_in[23];
  const float* b_v2       = (const float*)d_in[24];
  const float* W_pgen     = (const float*)d_in[25];
  const float* b_pgen     = (const float*)d_in[26];
  float* out = (float*)d_out;
  float* ws  = (float*)d_ws;
  if (ws_size < (size_t)WS_TOTAL * sizeof(float)) return;

  k_prep<<<dim3(627), dim3(256), 0, stream>>>(w_hh0, w_ih1, w_hh1, W_attn, W_v1, W_reduce, ws);
  k_reduce_enc<<<dim3(32), dim3(256), 0, stream>>>(hidden_enc, cell_enc, b_reduce, ws);
  k_enc_base<<<dim3(25, 2, 16), dim3(256), 0, stream>>>(output_enc, W_attn, b_attn, ws);
  for (int p = 0; p <= T_; ++p)
    k_lstm2<<<dim3(48), dim3(256), 0, stream>>>(input_dec, w_ih0, b_ih0, b_hh0,
                                                b_ih1, b_hh1, ws, out, p);
  k_odp<<<dim3(512), dim3(256), 0, stream>>>(ws);
  k_attn<<<dim3(16), dim3(1024), 0, stream>>>(att_mask, W_attn, w_attn_out, out, ws);
  k_ctx<<<dim3(16, 2, 8), dim3(256), 0, stream>>>(output_enc, ws, out);
  k_pgen_h1<<<dim3(512), dim3(256), 0, stream>>>(input_dec, emb, b_v1, W_pgen, b_pgen, out, ws);
  k_logits<<<dim3(782, 8), dim3(256), 0, stream>>>(W_v2, b_v2, ws, out);
  k_finalize<<<dim3(50, 512), dim3(256), 0, stream>>>(out, ws);
  k_scatter<<<dim3(800), dim3(256), 0, stream>>>(real_index, ws, out);
}

// Round 4
// 865.777 us; speedup vs baseline: 1.6810x; 1.3634x over previous
//
#include <hip/hip_runtime.h>
#include <math.h>

#define S_   400
#define B_   16
#define T_   32
#define H_   256
#define A_   100
#define G_   50
#define VF_  100
#define V_   50000
#define BV_  50050

#define L2E   1.44269504088896f
#define L2E2  2.88539008177793f

// ---- ws offsets (floats) ----
#define WS_H0S   0          // [2][256][16] h-major state, parity buffered
#define WS_C0S   8192
#define WS_H1S   16384
#define WS_C1S   24576
#define WS_Y0    32768      // [32][256][16] layer0 outputs (h-major)
#define WS_OD    163840     // [32][256][16] layer1 outputs (h-major)
#define WS_WT0   294912     // [256][1024] permuted k-major w_hh0
#define WS_WTI1  557056     // [256][1024] permuted k-major w_ih1
#define WS_WTH1  819200     // [256][1024] permuted k-major w_hh1
#define WS_WODT  1081344    // [256][100]  W_attn[:,512:768]^T
#define WS_WV1T  1106944    // [768][100]  W_v1^T
#define WS_WRT   1183744    // [512][256]  W_reduce^T
#define WS_BASE2 1314816    // [16][100][400]  (enc@Wattn + b_attn)*2log2e
#define WS_ODP2  1954816    // [32*16][100]
#define WS_ATTN  2006016    // [16][32][400]
#define WS_H1B   2210816    // [512][128] bf16 (stored as shorts) = 32768 float slots
#define WS_PGEN  2243584    // [512]
#define WS_VSUM  2244096    // [512]
#define WS_TOTAL 2244608

// ---- out offsets (floats) ----
#define OUT_CL   25625600
#define OUT_COV  25626112
#define OUT_HID  25632512
#define OUT_CELL 25640704
// first 8*512*512 floats of out are used as ctx-partial scratch (overwritten by vocab pass B later)
#define CTXP_SZ  262144

typedef __attribute__((ext_vector_type(8))) short bf16x8;
typedef __attribute__((ext_vector_type(4))) float f32x4;

__device__ __forceinline__ float fexp2(float x){ return __builtin_amdgcn_exp2f(x); }
__device__ __forceinline__ float frcp (float x){ return __builtin_amdgcn_rcpf(x); }
__device__ __forceinline__ float sigm (float x){ return frcp(1.f + fexp2(-L2E*x)); }
__device__ __forceinline__ float tanhx(float x){ return fmaf(-2.f, frcp(1.f + fexp2(L2E2*x)), 1.f); }
__device__ __forceinline__ short cvt_bf16(float x){
  unsigned u = __float_as_uint(x);
  u += 0x7FFFu + ((u >> 16) & 1u);
  return (short)(u >> 16);
}

__device__ __forceinline__ float bredSum(float v, float* red){
  #pragma unroll
  for (int m = 32; m >= 1; m >>= 1) v += __shfl_xor(v, m);
  __syncthreads();
  if ((threadIdx.x & 63) == 0) red[threadIdx.x >> 6] = v;
  __syncthreads();
  float r = 0.f;
  int nw = blockDim.x >> 6;
  for (int k = 0; k < nw; ++k) r += red[k];
  return r;
}

// ---------------- prep: tiled permuted transposes + small transposes + zero ----------------
__global__ __launch_bounds__(256) void k_prep(const float* __restrict__ w_hh0,
    const float* __restrict__ w_ih1, const float* __restrict__ w_hh1,
    const float* __restrict__ W_attn, const float* __restrict__ W_v1,
    const float* __restrict__ W_reduce, float* __restrict__ ws){
  int bx = blockIdx.x, tid = threadIdx.x;
  __shared__ float tile[64*65];
  if (bx < 192){
    int m = bx >> 6, t6 = bx & 63;
    int kb = t6 & 3, cb = t6 >> 2;
    const float* src = (m == 0) ? w_hh0 : (m == 1) ? w_ih1 : w_hh1;
    int dstoff = (m == 0) ? WS_WT0 : (m == 1) ? WS_WTI1 : WS_WTH1;
    for (int o = tid; o < 4096; o += 256){
      int cc = o >> 6, kk = o & 63;
      int c = cb*64 + cc;
      int j;
      if (m == 0){ int w = c >> 6, l = c & 63; j = (l>>4)*256 + w*16 + (l&15); }
      else       { int u = c >> 5, idx = c & 31; j = (idx>>3)*256 + u*8 + (idx&7); }
      tile[cc*65 + kk] = src[j*256 + kb*64 + kk];
    }
    __syncthreads();
    for (int o = tid; o < 4096; o += 256){
      int kk = o >> 6, cc = o & 63;
      ws[dstoff + (kb*64 + kk)*1024 + cb*64 + cc] = tile[cc*65 + kk];
    }
    return;
  }
  if (bx < 224){
    int t6 = bx - 192;      // W_reduce [256 j][512 k] -> WRT [512 k][256 j]
    int kb = t6 & 7, jb = t6 >> 3;
    for (int o = tid; o < 4096; o += 256){
      int jj = o >> 6, kk = o & 63;
      tile[jj*65 + kk] = W_reduce[(jb*64 + jj)*512 + kb*64 + kk];
    }
    __syncthreads();
    for (int o = tid; o < 4096; o += 256){
      int kk = o >> 6, jj = o & 63;
      ws[WS_WRT + (kb*64 + kk)*256 + jb*64 + jj] = tile[jj*65 + kk];
    }
    return;
  }
  int i = (bx - 224)*256 + tid;
  if (i < 25600){ int k = i/100, a = i%100; ws[WS_WODT + i] = W_attn[a*769 + 512 + k]; return; }
  i -= 25600;
  if (i < 76800){ int k = i/100, f = i%100; ws[WS_WV1T + i] = W_v1[f*768 + k]; return; }
  i -= 76800;
  if (i < 512){ ws[WS_VSUM + i] = 0.f; return; }
}

// ---------------- encoder state reduce (writes h-major state) ----------------
__global__ __launch_bounds__(256) void k_reduce_enc(const float* __restrict__ he,
    const float* __restrict__ ce, const float* __restrict__ b_reduce, float* __restrict__ ws){
  int bx = blockIdx.x;            // 32 blocks: l = bx>>4, b = bx&15
  int l = bx >> 4, b = bx & 15, j = threadIdx.x;
  const float* wrt = ws + WS_WRT;
  const float* h_a = he + (l*B_ + b)*H_;
  const float* h_b = he + ((l+2)*B_ + b)*H_;
  const float* c_a = ce + (l*B_ + b)*H_;
  const float* c_b = ce + ((l+2)*B_ + b)*H_;
  float ah = b_reduce[j], ac = b_reduce[j];
  for (int k = 0; k < 256; ++k){
    float w0 = wrt[k*256 + j];
    float w1 = wrt[(256+k)*256 + j];
    ah += w0*h_a[k] + w1*h_b[k];
    ac += w0*c_a[k] + w1*c_b[k];
  }
  if (l == 0){ ws[WS_H0S + j*16 + b] = ah; ws[WS_C0S + j*16 + b] = ac; }
  else       { ws[WS_H1S + j*16 + b] = ah; ws[WS_C1S + j*16 + b] = ac; }
}

// ---------------- enc_base = (output_enc @ W_attn[:, :512]^T + b_attn)*2log2e ----------------
__global__ __launch_bounds__(256) void k_enc_base(const float* __restrict__ enc,
    const float* __restrict__ W_attn, const float* __restrict__ b_attn, float* __restrict__ ws){
  int st = blockIdx.x, ah = blockIdx.y, b = blockIdx.z;   // (25, 2, 16)
  int s_base = st*16;
  __shared__ float encs[16][132];
  __shared__ float was[50][132];
  int tid = threadIdx.x;
  bool act = tid < 200;
  int sg = tid & 7, ag = tid >> 3;
  int sl = sg*2, al = ag*2;
  float acc00=0.f, acc01=0.f, acc10=0.f, acc11=0.f;
  for (int kc = 0; kc < 4; ++kc){
    int k0 = kc*128;
    __syncthreads();
    for (int o = tid; o < 512; o += 256){
      int r = o >> 5, c4 = (o & 31)*4;
      float4 v = *(const float4*)(enc + ((s_base + r)*B_ + b)*512 + k0 + c4);
      *(float4*)&encs[r][c4] = v;
    }
    for (int o = tid; o < 6400; o += 256){
      int r = o >> 7, c = o & 127;
      was[r][c] = W_attn[(ah*50 + r)*769 + k0 + c];
    }
    __syncthreads();
    if (act){
      for (int k = 0; k < 128; ++k){
        float e0 = encs[sl][k], e1 = encs[sl+1][k];
        float w0 = was[al][k],  w1 = was[al+1][k];
        acc00 = fmaf(e0, w0, acc00); acc01 = fmaf(e0, w1, acc01);
        acc10 = fmaf(e1, w0, acc10); acc11 = fmaf(e1, w1, acc11);
      }
    }
  }
  if (act){
    int a = ah*50 + al, s = s_base + sl;
    float* bpp = ws + WS_BASE2 + (b*A_)*S_;
    bpp[(a  )*S_ + s  ] = (acc00 + b_attn[a  ]) * L2E2;
    bpp[(a+1)*S_ + s  ] = (acc01 + b_attn[a+1]) * L2E2;
    bpp[(a  )*S_ + s+1] = (acc10 + b_attn[a  ]) * L2E2;
    bpp[(a+1)*S_ + s+1] = (acc11 + b_attn[a+1]) * L2E2;
  }
}

// ---------------- LSTM phase p: WGs 0-15 layer0 step p, WGs 16-47 layer1 step p-1 ----------------
__global__ __launch_bounds__(256) void k_lstm2(const float* __restrict__ input_dec,
    const float* __restrict__ w_ih0, const float* __restrict__ b_ih0, const float* __restrict__ b_hh0,
    const float* __restrict__ b_ih1, const float* __restrict__ b_hh1,
    float* __restrict__ ws, float* __restrict__ out, int p){
  int wgs = blockIdx.x;
  int tid = threadIdx.x;
  __shared__ float hs[4096];
  __shared__ float ys[4096];
  __shared__ float gv[1088];
  __shared__ float xs[16];
  if (wgs < 16){
    if (p >= T_) return;
    int w = wgs;
    int par = p & 1, npar = par ^ 1;
    for (int o = tid; o < 4096; o += 256) hs[o] = ws[WS_H0S + par*4096 + o];
    if (tid < 16) xs[tid] = input_dec[p*16 + tid];
    __syncthreads();
    int bg = tid >> 6, l = tid & 63;
    int g = l >> 4, hh = l & 15;
    int j = g*256 + w*16 + hh;
    float bias = b_ih0[j] + b_hh0[j];
    float wih = w_ih0[j];
    float x0 = xs[bg*4+0], x1 = xs[bg*4+1], x2 = xs[bg*4+2], x3 = xs[bg*4+3];
    float a0 = fmaf(x0, wih, bias);
    float a1 = fmaf(x1, wih, bias);
    float a2 = fmaf(x2, wih, bias);
    float a3 = fmaf(x3, wih, bias);
    const float* wp = ws + WS_WT0 + w*64 + l;
    #pragma unroll 8
    for (int k = 0; k < 256; ++k){
      float wv = wp[k*1024];
      float4 hv = *(const float4*)&hs[k*16 + bg*4];
      a0 = fmaf(wv, hv.x, a0); a1 = fmaf(wv, hv.y, a1);
      a2 = fmaf(wv, hv.z, a2); a3 = fmaf(wv, hv.w, a3);
    }
    int gb = (g*16 + hh)*17 + bg*4;
    gv[gb+0] = a0; gv[gb+1] = a1; gv[gb+2] = a2; gv[gb+3] = a3;
    __syncthreads();
    int b = tid & 15, h2 = tid >> 4;
    float gi = gv[(0*16+h2)*17 + b], gf = gv[(1*16+h2)*17 + b];
    float gg = gv[(2*16+h2)*17 + b], go = gv[(3*16+h2)*17 + b];
    int hidx = w*16 + h2;
    float cold = ws[WS_C0S + par*4096 + hidx*16 + b];
    float ig = sigm(gi), fg = sigm(gf), gt = tanhx(gg), og = sigm(go);
    float cn = fmaf(fg, cold, ig*gt);
    float hn = og * tanhx(cn);
    ws[WS_C0S + npar*4096 + hidx*16 + b] = cn;
    ws[WS_H0S + npar*4096 + hidx*16 + b] = hn;
    ws[WS_Y0 + p*4096 + hidx*16 + b] = hn;
    if (p == T_-1){
      out[OUT_HID  + b*256 + hidx] = hn;
      out[OUT_CELL + b*256 + hidx] = cn;
    }
  } else {
    int q = p - 1;
    if (q < 0) return;
    int u = wgs - 16;
    int par = q & 1, npar = par ^ 1;
    for (int o = tid; o < 4096; o += 256){
      ys[o] = ws[WS_Y0 + q*4096 + o];
      hs[o] = ws[WS_H1S + par*4096 + o];
    }
    __syncthreads();
    int bg = tid >> 5, idx = tid & 31;
    int g = idx >> 3, hh = idx & 7;
    int j = g*256 + u*8 + hh;
    float bias = b_ih1[j] + b_hh1[j];
    float ai0 = bias, ah0 = 0.f, ai1 = bias, ah1 = 0.f;
    const float* wip = ws + WS_WTI1 + u*32 + idx;
    const float* whp = ws + WS_WTH1 + u*32 + idx;
    #pragma unroll 8
    for (int k = 0; k < 256; ++k){
      float wi = wip[k*1024];
      float wh = whp[k*1024];
      float2 yv = *(const float2*)&ys[k*16 + bg*2];
      float2 hv = *(const float2*)&hs[k*16 + bg*2];
      ai0 = fmaf(wi, yv.x, ai0); ai1 = fmaf(wi, yv.y, ai1);
      ah0 = fmaf(wh, hv.x, ah0); ah1 = fmaf(wh, hv.y, ah1);
    }
    int gb = g*136 + hh*17 + bg*2;
    gv[gb+0] = ai0 + ah0; gv[gb+1] = ai1 + ah1;
    __syncthreads();
    if (tid < 128){
      int b = tid & 15, h2 = (tid >> 4) & 7;
      float gi = gv[0*136 + h2*17 + b], gf = gv[1*136 + h2*17 + b];
      float gg = gv[2*136 + h2*17 + b], go = gv[3*136 + h2*17 + b];
      int hidx = u*8 + h2;
      float cold = ws[WS_C1S + par*4096 + hidx*16 + b];
      float ig = sigm(gi), fg = sigm(gf), gt = tanhx(gg), og = sigm(go);
      float cn = fmaf(fg, cold, ig*gt);
      float hn = og * tanhx(cn);
      ws[WS_C1S + npar*4096 + hidx*16 + b] = cn;
      ws[WS_H1S + npar*4096 + hidx*16 + b] = hn;
      ws[WS_OD + q*4096 + hidx*16 + b] = hn;
      if (q == T_-1){
        out[OUT_HID  + 4096 + b*256 + hidx] = hn;
        out[OUT_CELL + 4096 + b*256 + hidx] = cn;
      }
    }
  }
}

// ---------------- odp2[t*16+b][a] = (od @ W_attn[:,512:768]^T) * 2log2e ----------------
__global__ __launch_bounds__(256) void k_odp(float* __restrict__ ws){
  int row = blockIdx.x;        // 512 = t*16+b
  int t = row >> 4, b = row & 15;
  int tid = threadIdx.x;
  __shared__ float odl[256];
  odl[tid] = ws[WS_OD + t*4096 + tid*16 + b];
  __syncthreads();
  if (tid < 100){
    float acc = 0.f;
    for (int k = 0; k < 256; ++k) acc = fmaf(ws[WS_WODT + k*100 + tid], odl[k], acc);
    ws[WS_ODP2 + row*100 + tid] = acc * L2E2;
  }
}

// ---------------- attention recurrence: one WG per batch, base2 in registers ----------------
__global__ __launch_bounds__(1024) void k_attn(const float* __restrict__ amask,
    const float* __restrict__ W_attn, const float* __restrict__ wout_g,
    float* __restrict__ out, float* __restrict__ ws){
  int b = blockIdx.x;
  int tid = threadIdx.x;
  int wv = tid >> 6, l = tid & 63;
  int half = wv & 1, sblk = wv >> 1;
  int s = sblk*64 + l;
  bool cvalid = (sblk < 7) && (s < 400);
  int a0 = half*50;
  __shared__ float cov[400], eh[2][400], amL[400], red[2][8];
  __shared__ float4 f4[100];
  __shared__ float wcwo[200];
  if (tid < 100){
    wcwo[tid]       = W_attn[tid*769 + 768] * L2E2;
    wcwo[100 + tid] = -2.f * wout_g[tid];
  }
  if (tid < 400){ cov[tid] = 0.f; amL[tid] = amask[tid*16 + b] * L2E; }
  __syncthreads();
  float woSum = 0.f;
  for (int a = 0; a < 100; ++a) woSum -= 0.5f * wcwo[100 + a];
  float ba[50];
  #pragma unroll
  for (int i = 0; i < 50; ++i)
    ba[i] = cvalid ? ws[WS_BASE2 + (b*100 + a0 + i)*400 + s] : 0.f;

  for (int t = 0; t < T_; ++t){
    if (tid < 100){
      float od = ws[WS_ODP2 + (t*16 + b)*100 + tid];
      f4[tid] = make_float4(od, wcwo[tid], wcwo[100 + tid], 0.f);
    }
    __syncthreads();     // S1: f4 ready, cov stable
    float ep = 0.f;
    if (cvalid){
      float cv = cov[s];
      #pragma unroll
      for (int i = 0; i < 50; ++i){
        float4 q = f4[a0 + i];
        float x = fmaf(q.y, cv, ba[i] + q.x);
        ep = fmaf(q.z, frcp(1.f + fexp2(x)), ep);
      }
      eh[half][s] = ep;
    }
    __syncthreads();     // S2
    float ex = 0.f;
    if (tid < 400){
      float et = woSum + eh[0][tid] + eh[1][tid];
      ex = fexp2(fmaf(et, L2E, amL[tid]));
    }
    float ps = ex;
    #pragma unroll
    for (int m = 32; m >= 1; m >>= 1) ps += __shfl_xor(ps, m);
    if (l == 0 && wv < 7) red[0][wv] = ps;
    __syncthreads();     // S3
    float den = ((red[0][0]+red[0][1])+(red[0][2]+red[0][3]))
              + ((red[0][4]+red[0][5])+red[0][6]);
    float inv = frcp(den);
    float at = ex * inv;
    float cl = 0.f;
    if (tid < 400){
      float cvo = cov[tid];
      cl = fminf(at, cvo);
      cov[tid] = cvo + at;
      ws[WS_ATTN + (b*32 + t)*400 + tid] = at;
    }
    float p2 = cl;
    #pragma unroll
    for (int m = 32; m >= 1; m >>= 1) p2 += __shfl_xor(p2, m);
    if (l == 0 && wv < 7) red[1][wv] = p2;
    __syncthreads();     // S4
    if (tid == 0){
      float cls = ((red[1][0]+red[1][1])+(red[1][2]+red[1][3]))
                + ((red[1][4]+red[1][5])+red[1][6]);
      out[OUT_CL + t*16 + b] = cls;
    }
  }
  if (tid < 400) out[OUT_COV + tid*16 + b] = cov[tid];
}

// ---------------- context partials into out-scratch: ctxp[sc][t*16+b][512] ----------------
__global__ __launch_bounds__(256) void k_ctx(const float* __restrict__ enc,
    const float* __restrict__ ws, float* __restrict__ ctxp){
  int b = blockIdx.x, jh = blockIdx.y, sc = blockIdx.z;   // (16,2,8)
  int tid = threadIdx.x;
  __shared__ float at[32*52];
  for (int o = tid; o < 1600; o += 256){
    int t = o/50, s2 = o%50;
    at[t*52 + s2] = ws[WS_ATTN + (b*32 + t)*400 + sc*50 + s2];
  }
  __syncthreads();
  int j = jh*256 + tid;
  float acc[32];
  #pragma unroll
  for (int t = 0; t < 32; ++t) acc[t] = 0.f;
  for (int s2 = 0; s2 < 50; ++s2){
    float evv = enc[((sc*50 + s2)*16 + b)*512 + j];
    #pragma unroll
    for (int t = 0; t < 32; ++t) acc[t] = fmaf(at[t*52 + s2], evv, acc[t]);
  }
  #pragma unroll
  for (int t = 0; t < 32; ++t)
    ctxp[sc*CTXP_SZ + (t*16 + b)*512 + j] = acc[t];
}

// ---------------- pgen + h1 (vocab hidden, bf16 padded) per (t,b) ----------------
__global__ __launch_bounds__(256) void k_pgen_h1(const float* __restrict__ input_dec,
    const float* __restrict__ emb, const float* __restrict__ b_v1,
    const float* __restrict__ W_pgen, const float* __restrict__ b_pgen,
    const float* __restrict__ ctxp, float* __restrict__ ws){
  int row = blockIdx.x, tid = threadIdx.x;
  int t = row >> 4, b = row & 15;
  __shared__ float pv[768], el[50], red[16];
  pv[tid] = ws[WS_OD + t*4096 + tid*16 + b];
  float c0 = 0.f, c1 = 0.f;
  #pragma unroll
  for (int sc = 0; sc < 8; ++sc){
    c0 += ctxp[sc*CTXP_SZ + row*512 + tid];
    c1 += ctxp[sc*CTXP_SZ + row*512 + 256 + tid];
  }
  pv[256 + tid] = c0;
  pv[512 + tid] = c1;
  int tok = (int)input_dec[row];
  if (tid < 50) el[tid] = emb[tok*50 + tid];
  __syncthreads();
  float p = 0.f;
  for (int k = tid; k < 818; k += 256){
    float x = (k < 512) ? pv[256 + k] : (k < 768) ? pv[k - 512] : el[k - 768];
    p = fmaf(W_pgen[k], x, p);
  }
  p = bredSum(p, red);
  if (tid == 0) ws[WS_PGEN + row] = sigm(p + b_pgen[0]);
  short* hb = (short*)(ws + WS_H1B);
  if (tid < 100){
    float acc = b_v1[tid];
    for (int k = 0; k < 768; ++k) acc = fmaf(ws[WS_WV1T + k*100 + tid], pv[k], acc);
    hb[row*128 + tid] = cvt_bf16(acc);
  } else if (tid < 128){
    hb[row*128 + tid] = 0;
  }
}

// ---------------- vocab GEMM via MFMA: shared frag loader ----------------
__device__ __forceinline__ void load_bfrags(const float* __restrict__ W_v2,
    const float* __restrict__ b_v2, int v0, int lane_m, int lq,
    bf16x8 bf[4][4], float bias[4], int vv[4]){
  #pragma unroll
  for (int nt = 0; nt < 4; ++nt){
    int v = v0 + nt*16 + lane_m;
    vv[nt] = v;
    bool vok = v < V_;
    bias[nt] = vok ? b_v2[v] : 0.f;
    const float* wp = W_v2 + (size_t)v*100;
    #pragma unroll
    for (int kk = 0; kk < 4; ++kk){
      int k0 = kk*32 + lq*8;
      float x[8];
      if (vok && kk < 3){
        float4 p0 = *(const float4*)(wp + k0);
        float4 p1 = *(const float4*)(wp + k0 + 4);
        x[0]=p0.x; x[1]=p0.y; x[2]=p0.z; x[3]=p0.w;
        x[4]=p1.x; x[5]=p1.y; x[6]=p1.z; x[7]=p1.w;
      } else if (vok && k0 == 96){
        float4 p0 = *(const float4*)(wp + 96);
        x[0]=p0.x; x[1]=p0.y; x[2]=p0.z; x[3]=p0.w;
        x[4]=0.f; x[5]=0.f; x[6]=0.f; x[7]=0.f;
      } else {
        #pragma unroll
        for (int e = 0; e < 8; ++e) x[e] = 0.f;
      }
      bf16x8 r;
      #pragma unroll
      for (int e = 0; e < 8; ++e) r[e] = cvt_bf16(x[e]);
      bf[nt][kk] = r;
    }
  }
}

// ---------------- pass A: per-row exp2-sums of logits (no materialization) ----------------
__global__ __launch_bounds__(256) void k_vsum(const float* __restrict__ W_v2,
    const float* __restrict__ b_v2, float* __restrict__ ws){
  int tid = threadIdx.x;
  int wave = tid >> 6, l = tid & 63;
  int lane_m = l & 15, lq = l >> 4;
  int v0 = blockIdx.x*256 + wave*64;
  int r0base = blockIdx.y*256;
  __shared__ float rsum[256];
  for (int o = tid; o < 256; o += 256) rsum[o] = 0.f;
  bf16x8 bf[4][4];
  float bias[4];
  int vv[4];
  load_bfrags(W_v2, b_v2, v0, lane_m, lq, bf, bias, vv);
  __syncthreads();
  const short* hws = (const short*)(ws + WS_H1B);
  for (int rg = 0; rg < 16; ++rg){
    int r0 = r0base + rg*16;
    bf16x8 af[4];
    #pragma unroll
    for (int kk = 0; kk < 4; ++kk)
      af[kk] = *(const bf16x8*)(hws + (r0 + lane_m)*128 + kk*32 + lq*8);
    float es[4] = {0.f, 0.f, 0.f, 0.f};
    #pragma unroll
    for (int nt = 0; nt < 4; ++nt){
      f32x4 c = {bias[nt], bias[nt], bias[nt], bias[nt]};
      #pragma unroll
      for (int kk = 0; kk < 4; ++kk)
        c = __builtin_amdgcn_mfma_f32_16x16x32_bf16(af[kk], bf[nt][kk], c, 0, 0, 0);
      if (vv[nt] < V_){
        #pragma unroll
        for (int j = 0; j < 4; ++j) es[j] += fexp2(c[j] * L2E);
      }
    }
    #pragma unroll
    for (int m = 1; m <= 8; m <<= 1){
      #pragma unroll
      for (int j = 0; j < 4; ++j) es[j] += __shfl_xor(es[j], m);
    }
    if (lane_m == 0){
      #pragma unroll
      for (int j = 0; j < 4; ++j)
        atomicAdd(&rsum[rg*16 + lq*4 + j], es[j]);
    }
  }
  __syncthreads();
  if (tid < 256) atomicAdd(ws + WS_VSUM + r0base + tid, rsum[tid]);
}

// ---------------- pass B: recompute logits, write softmax*pgen directly ----------------
__global__ __launch_bounds__(256) void k_vwrite(const float* __restrict__ W_v2,
    const float* __restrict__ b_v2, const float* __restrict__ ws, float* __restrict__ out){
  int tid = threadIdx.x;
  int wave = tid >> 6, l = tid & 63;
  int lane_m = l & 15, lq = l >> 4;
  int v0 = blockIdx.x*256 + wave*64;
  int r0base = blockIdx.y*128;
  __shared__ float scs[128];
  if (tid < 128){
    int r = r0base + tid;
    scs[tid] = ws[WS_PGEN + r] / ws[WS_VSUM + r];
  }
  bf16x8 bf[4][4];
  float bias[4];
  int vv[4];
  load_bfrags(W_v2, b_v2, v0, lane_m, lq, bf, bias, vv);
  __syncthreads();
  const short* hws = (const short*)(ws + WS_H1B);
  for (int rg = 0; rg < 8; ++rg){
    int r0 = r0base + rg*16;
    bf16x8 af[4];
    #pragma unroll
    for (int kk = 0; kk < 4; ++kk)
      af[kk] = *(const bf16x8*)(hws + (r0 + lane_m)*128 + kk*32 + lq*8);
    #pragma unroll
    for (int nt = 0; nt < 4; ++nt){
      f32x4 c = {bias[nt], bias[nt], bias[nt], bias[nt]};
      #pragma unroll
      for (int kk = 0; kk < 4; ++kk)
        c = __builtin_amdgcn_mfma_f32_16x16x32_bf16(af[kk], bf[nt][kk], c, 0, 0, 0);
      int v = vv[nt];
      if (v < BV_){
        bool gen = v < V_;
        #pragma unroll
        for (int j = 0; j < 4; ++j){
          int rloc = rg*16 + lq*4 + j;
          float sc = scs[rloc];
          float p = gen ? fexp2(c[j] * L2E) * sc : 0.f;
          out[(size_t)(r0base + rloc)*BV_ + v] = p;
        }
      }
    }
  }
}

// ---------------- copy-distribution scatter ----------------
__global__ __launch_bounds__(256) void k_scatter(const int* __restrict__ real_index,
    const float* __restrict__ ws, float* __restrict__ out){
  int i = blockIdx.x*256 + threadIdx.x;   // 16*32*400
  int b = i / 12800, r = i % 12800, t = r / 400, s = r % 400;
  float at = ws[WS_ATTN + i];
  float w = 1.f - ws[WS_PGEN + t*16 + b];
  int col = real_index[s*16 + b];
  atomicAdd(out + (size_t)(t*16 + b)*BV_ + col, at*w);
}

extern "C" void kernel_launch(void* const* d_in, const int* in_sizes, int n_in,
                              void* d_out, int out_size, void* d_ws, size_t ws_size,
                              hipStream_t stream){
  const float* output_enc = (const float*)d_in[0];
  const int*   real_index = (const int*)d_in[1];
  const float* input_dec  = (const float*)d_in[3];
  const float* hidden_enc = (const float*)d_in[4];
  const float* cell_enc   = (const float*)d_in[5];
  const float* att_mask   = (const float*)d_in[6];
  const float* emb        = (const float*)d_in[7];
  const float* W_reduce   = (const float*)d_in[8];
  const float* b_reduce   = (const float*)d_in[9];
  const float* w_ih0      = (const float*)d_in[10];
  const float* w_hh0      = (const float*)d_in[11];
  const float* b_ih0      = (const float*)d_in[12];
  const float* b_hh0      = (const float*)d_in[13];
  const float* w_ih1      = (const float*)d_in[14];
  const float* w_hh1      = (const float*)d_in[15];
  const float* b_ih1      = (const float*)d_in[16];
  const float* b_hh1      = (const float*)d_in[17];
  const float* W_attn     = (const float*)d_in[18];
  const float* b_attn     = (const float*)d_in[19];
  const float* w_attn_out = (const float*)d_in[20];
  const float* W_v1       = (const float*)d_in[21];
  const float* b_v1       = (const float*)d_in[22];
  const float* W_v2       = (const float*)d_in[23];
  const float* b_v2       = (const float*)d_in[24];
  const float* W_pgen     = (const float*)d_in[25];
  const float* b_pgen     = (const float*)d_in[26];
  float* out = (float*)d_out;
  float* ws  = (float*)d_ws;
  if (ws_size < (size_t)WS_TOTAL * sizeof(float)) return;

  k_prep<<<dim3(627), dim3(256), 0, stream>>>(w_hh0, w_ih1, w_hh1, W_attn, W_v1, W_reduce, ws);
  k_reduce_enc<<<dim3(32), dim3(256), 0, stream>>>(hidden_enc, cell_enc, b_reduce, ws);
  k_enc_base<<<dim3(25, 2, 16), dim3(256), 0, stream>>>(output_enc, W_attn, b_attn, ws);
  for (int p = 0; p <= T_; ++p)
    k_lstm2<<<dim3(48), dim3(256), 0, stream>>>(input_dec, w_ih0, b_ih0, b_hh0,
                                                b_ih1, b_hh1, ws, out, p);
  k_odp<<<dim3(512), dim3(256), 0, stream>>>(ws);
  k_attn<<<dim3(16), dim3(1024), 0, stream>>>(att_mask, W_attn, w_attn_out, out, ws);
  k_ctx<<<dim3(16, 2, 8), dim3(256), 0, stream>>>(output_enc, ws, out);
  k_pgen_h1<<<dim3(512), dim3(256), 0, stream>>>(input_dec, emb, b_v1, W_pgen, b_pgen, out, ws);
  k_vsum<<<dim3(196, 2), dim3(256), 0, stream>>>(W_v2, b_v2, ws);
  k_vwrite<<<dim3(196, 4), dim3(256), 0, stream>>>(W_v2, b_v2, ws, out);
  k_scatter<<<dim3(800), dim3(256), 0, stream>>>(real_index, ws, out);
}

// Round 5
// 840.146 us; speedup vs baseline: 1.7323x; 1.0305x over previous
//
#include <hip/hip_runtime.h>
#include <math.h>

#define S_   400
#define B_   16
#define T_   32
#define H_   256
#define A_   100
#define G_   50
#define VF_  100
#define V_   50000
#define BV_  50050

#define L2E   1.44269504088896f
#define L2E2  2.88539008177793f

// ---- ws offsets (floats) ----
#define WS_H0S   0          // [2][256][16] h-major state, parity buffered
#define WS_C0S   8192
#define WS_H1S   16384
#define WS_C1S   24576
#define WS_Y0    32768      // [32][256][16] layer0 outputs (h-major)
#define WS_OD    163840     // [32][256][16] layer1 outputs (h-major)
#define WS_WT0   294912     // [256][1024] permuted k-major w_hh0
#define WS_WTI1  557056     // [256][1024] permuted k-major w_ih1
#define WS_WTH1  819200     // [256][1024] permuted k-major w_hh1
#define WS_WODT  1081344    // [256][100]  W_attn[:,512:768]^T
#define WS_WV1T  1106944    // [768][100]  W_v1^T
#define WS_WRT   1183744    // [512][256]  W_reduce^T
#define WS_BASE2 1314816    // [16][100][400]  (enc@Wattn + b_attn)*2log2e
#define WS_ODP2  1954816    // [32*16][100]
#define WS_ATTN  2006016    // [16][32][400]
#define WS_H1B   2210816    // [512][128] bf16 (stored as shorts) = 32768 float slots
#define WS_PGEN  2243584    // [512]
#define WS_VSUM  2244096    // [512]
#define WS_TOTAL 2244608

// ---- out offsets (floats) ----
#define OUT_CL   25625600
#define OUT_COV  25626112
#define OUT_HID  25632512
#define OUT_CELL 25640704
// first 8*512*512 floats of out are used as ctx-partial scratch (overwritten by vocab pass B later)
#define CTXP_SZ  262144

typedef __attribute__((ext_vector_type(8))) short bf16x8;
typedef __attribute__((ext_vector_type(4))) float f32x4;

__device__ __forceinline__ float fexp2(float x){ return __builtin_amdgcn_exp2f(x); }
__device__ __forceinline__ float frcp (float x){ return __builtin_amdgcn_rcpf(x); }
__device__ __forceinline__ float sigm (float x){ return frcp(1.f + fexp2(-L2E*x)); }
__device__ __forceinline__ float tanhx(float x){ return fmaf(-2.f, frcp(1.f + fexp2(L2E2*x)), 1.f); }
__device__ __forceinline__ short cvt_bf16(float x){
  unsigned u = __float_as_uint(x);
  u += 0x7FFFu + ((u >> 16) & 1u);
  return (short)(u >> 16);
}

__device__ __forceinline__ float bredSum(float v, float* red){
  #pragma unroll
  for (int m = 32; m >= 1; m >>= 1) v += __shfl_xor(v, m);
  __syncthreads();
  if ((threadIdx.x & 63) == 0) red[threadIdx.x >> 6] = v;
  __syncthreads();
  float r = 0.f;
  int nw = blockDim.x >> 6;
  for (int k = 0; k < nw; ++k) r += red[k];
  return r;
}

// ---------------- prep: tiled permuted transposes + small transposes + zero ----------------
__global__ __launch_bounds__(256) void k_prep(const float* __restrict__ w_hh0,
    const float* __restrict__ w_ih1, const float* __restrict__ w_hh1,
    const float* __restrict__ W_attn, const float* __restrict__ W_v1,
    const float* __restrict__ W_reduce, float* __restrict__ ws){
  int bx = blockIdx.x, tid = threadIdx.x;
  __shared__ float tile[64*65];
  if (bx < 192){
    int m = bx >> 6, t6 = bx & 63;
    int kb = t6 & 3, cb = t6 >> 2;
    const float* src = (m == 0) ? w_hh0 : (m == 1) ? w_ih1 : w_hh1;
    int dstoff = (m == 0) ? WS_WT0 : (m == 1) ? WS_WTI1 : WS_WTH1;
    for (int o = tid; o < 4096; o += 256){
      int cc = o >> 6, kk = o & 63;
      int c = cb*64 + cc;
      int j;
      if (m == 0){ int w = c >> 6, l = c & 63; j = (l>>4)*256 + w*16 + (l&15); }
      else       { int u = c >> 5, idx = c & 31; j = (idx>>3)*256 + u*8 + (idx&7); }
      tile[cc*65 + kk] = src[j*256 + kb*64 + kk];
    }
    __syncthreads();
    for (int o = tid; o < 4096; o += 256){
      int kk = o >> 6, cc = o & 63;
      ws[dstoff + (kb*64 + kk)*1024 + cb*64 + cc] = tile[cc*65 + kk];
    }
    return;
  }
  if (bx < 224){
    int t6 = bx - 192;      // W_reduce [256 j][512 k] -> WRT [512 k][256 j]
    int kb = t6 & 7, jb = t6 >> 3;
    for (int o = tid; o < 4096; o += 256){
      int jj = o >> 6, kk = o & 63;
      tile[jj*65 + kk] = W_reduce[(jb*64 + jj)*512 + kb*64 + kk];
    }
    __syncthreads();
    for (int o = tid; o < 4096; o += 256){
      int kk = o >> 6, jj = o & 63;
      ws[WS_WRT + (kb*64 + kk)*256 + jb*64 + jj] = tile[jj*65 + kk];
    }
    return;
  }
  int i = (bx - 224)*256 + tid;
  if (i < 25600){ int k = i/100, a = i%100; ws[WS_WODT + i] = W_attn[a*769 + 512 + k]; return; }
  i -= 25600;
  if (i < 76800){ int k = i/100, f = i%100; ws[WS_WV1T + i] = W_v1[f*768 + k]; return; }
  i -= 76800;
  if (i < 512){ ws[WS_VSUM + i] = 0.f; return; }
}

// ---------------- encoder state reduce (writes h-major state) ----------------
__global__ __launch_bounds__(256) void k_reduce_enc(const float* __restrict__ he,
    const float* __restrict__ ce, const float* __restrict__ b_reduce, float* __restrict__ ws){
  int bx = blockIdx.x;            // 32 blocks: l = bx>>4, b = bx&15
  int l = bx >> 4, b = bx & 15, j = threadIdx.x;
  const float* wrt = ws + WS_WRT;
  const float* h_a = he + (l*B_ + b)*H_;
  const float* h_b = he + ((l+2)*B_ + b)*H_;
  const float* c_a = ce + (l*B_ + b)*H_;
  const float* c_b = ce + ((l+2)*B_ + b)*H_;
  float ah = b_reduce[j], ac = b_reduce[j];
  for (int k = 0; k < 256; ++k){
    float w0 = wrt[k*256 + j];
    float w1 = wrt[(256+k)*256 + j];
    ah += w0*h_a[k] + w1*h_b[k];
    ac += w0*c_a[k] + w1*c_b[k];
  }
  if (l == 0){ ws[WS_H0S + j*16 + b] = ah; ws[WS_C0S + j*16 + b] = ac; }
  else       { ws[WS_H1S + j*16 + b] = ah; ws[WS_C1S + j*16 + b] = ac; }
}

// ---------------- enc_base = (output_enc @ W_attn[:, :512]^T + b_attn)*2log2e ----------------
__global__ __launch_bounds__(256) void k_enc_base(const float* __restrict__ enc,
    const float* __restrict__ W_attn, const float* __restrict__ b_attn, float* __restrict__ ws){
  int st = blockIdx.x, ah = blockIdx.y, b = blockIdx.z;   // (25, 2, 16)
  int s_base = st*16;
  __shared__ float encs[16][132];
  __shared__ float was[50][132];
  int tid = threadIdx.x;
  bool act = tid < 200;
  int sg = tid & 7, ag = tid >> 3;
  int sl = sg*2, al = ag*2;
  float acc00=0.f, acc01=0.f, acc10=0.f, acc11=0.f;
  for (int kc = 0; kc < 4; ++kc){
    int k0 = kc*128;
    __syncthreads();
    for (int o = tid; o < 512; o += 256){
      int r = o >> 5, c4 = (o & 31)*4;
      float4 v = *(const float4*)(enc + ((s_base + r)*B_ + b)*512 + k0 + c4);
      *(float4*)&encs[r][c4] = v;
    }
    for (int o = tid; o < 6400; o += 256){
      int r = o >> 7, c = o & 127;
      was[r][c] = W_attn[(ah*50 + r)*769 + k0 + c];
    }
    __syncthreads();
    if (act){
      for (int k = 0; k < 128; ++k){
        float e0 = encs[sl][k], e1 = encs[sl+1][k];
        float w0 = was[al][k],  w1 = was[al+1][k];
        acc00 = fmaf(e0, w0, acc00); acc01 = fmaf(e0, w1, acc01);
        acc10 = fmaf(e1, w0, acc10); acc11 = fmaf(e1, w1, acc11);
      }
    }
  }
  if (act){
    int a = ah*50 + al, s = s_base + sl;
    float* bpp = ws + WS_BASE2 + (b*A_)*S_;
    bpp[(a  )*S_ + s  ] = (acc00 + b_attn[a  ]) * L2E2;
    bpp[(a+1)*S_ + s  ] = (acc01 + b_attn[a+1]) * L2E2;
    bpp[(a  )*S_ + s+1] = (acc10 + b_attn[a  ]) * L2E2;
    bpp[(a+1)*S_ + s+1] = (acc11 + b_attn[a+1]) * L2E2;
  }
}

// ---------------- LSTM phase p: WGs 0-15 layer0 step p, WGs 16-47 layer1 step p-1 ----------------
__global__ __launch_bounds__(256, 1) void k_lstm2(const float* __restrict__ input_dec,
    const float* __restrict__ w_ih0, const float* __restrict__ b_ih0, const float* __restrict__ b_hh0,
    const float* __restrict__ b_ih1, const float* __restrict__ b_hh1,
    float* __restrict__ ws, float* __restrict__ out, int p){
  int wgs = blockIdx.x;
  int tid = threadIdx.x;
  __shared__ float hs[4096];
  __shared__ float ys[4096];
  __shared__ float gv[1088];
  __shared__ float xs[16];
  if (wgs < 16){
    if (p >= T_) return;
    int w = wgs;
    int par = p & 1, npar = par ^ 1;
    for (int o = tid; o < 4096; o += 256) hs[o] = ws[WS_H0S + par*4096 + o];
    if (tid < 16) xs[tid] = input_dec[p*16 + tid];
    __syncthreads();
    int bg = tid >> 6, l = tid & 63;
    int g = l >> 4, hh = l & 15;
    int j = g*256 + w*16 + hh;
    float bias = b_ih0[j] + b_hh0[j];
    float wih = w_ih0[j];
    float x0 = xs[bg*4+0], x1 = xs[bg*4+1], x2 = xs[bg*4+2], x3 = xs[bg*4+3];
    float a0 = fmaf(x0, wih, bias);
    float a1 = fmaf(x1, wih, bias);
    float a2 = fmaf(x2, wih, bias);
    float a3 = fmaf(x3, wih, bias);
    const float* wp = ws + WS_WT0 + w*64 + l;
    #pragma unroll 32
    for (int k = 0; k < 256; ++k){
      float wv = wp[k*1024];
      float4 hv = *(const float4*)&hs[k*16 + bg*4];
      a0 = fmaf(wv, hv.x, a0); a1 = fmaf(wv, hv.y, a1);
      a2 = fmaf(wv, hv.z, a2); a3 = fmaf(wv, hv.w, a3);
    }
    int gb = (g*16 + hh)*17 + bg*4;
    gv[gb+0] = a0; gv[gb+1] = a1; gv[gb+2] = a2; gv[gb+3] = a3;
    __syncthreads();
    int b = tid & 15, h2 = tid >> 4;
    float gi = gv[(0*16+h2)*17 + b], gf = gv[(1*16+h2)*17 + b];
    float gg = gv[(2*16+h2)*17 + b], go = gv[(3*16+h2)*17 + b];
    int hidx = w*16 + h2;
    float cold = ws[WS_C0S + par*4096 + hidx*16 + b];
    float ig = sigm(gi), fg = sigm(gf), gt = tanhx(gg), og = sigm(go);
    float cn = fmaf(fg, cold, ig*gt);
    float hn = og * tanhx(cn);
    ws[WS_C0S + npar*4096 + hidx*16 + b] = cn;
    ws[WS_H0S + npar*4096 + hidx*16 + b] = hn;
    ws[WS_Y0 + p*4096 + hidx*16 + b] = hn;
    if (p == T_-1){
      out[OUT_HID  + b*256 + hidx] = hn;
      out[OUT_CELL + b*256 + hidx] = cn;
    }
  } else {
    int q = p - 1;
    if (q < 0) return;
    int u = wgs - 16;
    int par = q & 1, npar = par ^ 1;
    for (int o = tid; o < 4096; o += 256){
      ys[o] = ws[WS_Y0 + q*4096 + o];
      hs[o] = ws[WS_H1S + par*4096 + o];
    }
    __syncthreads();
    int bg = tid >> 5, idx = tid & 31;
    int g = idx >> 3, hh = idx & 7;
    int j = g*256 + u*8 + hh;
    float bias = b_ih1[j] + b_hh1[j];
    float ai0 = bias, ah0 = 0.f, ai1 = bias, ah1 = 0.f;
    const float* wip = ws + WS_WTI1 + u*32 + idx;
    const float* whp = ws + WS_WTH1 + u*32 + idx;
    #pragma unroll 16
    for (int k = 0; k < 256; ++k){
      float wi = wip[k*1024];
      float wh = whp[k*1024];
      float2 yv = *(const float2*)&ys[k*16 + bg*2];
      float2 hv = *(const float2*)&hs[k*16 + bg*2];
      ai0 = fmaf(wi, yv.x, ai0); ai1 = fmaf(wi, yv.y, ai1);
      ah0 = fmaf(wh, hv.x, ah0); ah1 = fmaf(wh, hv.y, ah1);
    }
    int gb = g*136 + hh*17 + bg*2;
    gv[gb+0] = ai0 + ah0; gv[gb+1] = ai1 + ah1;
    __syncthreads();
    if (tid < 128){
      int b = tid & 15, h2 = (tid >> 4) & 7;
      float gi = gv[0*136 + h2*17 + b], gf = gv[1*136 + h2*17 + b];
      float gg = gv[2*136 + h2*17 + b], go = gv[3*136 + h2*17 + b];
      int hidx = u*8 + h2;
      float cold = ws[WS_C1S + par*4096 + hidx*16 + b];
      float ig = sigm(gi), fg = sigm(gf), gt = tanhx(gg), og = sigm(go);
      float cn = fmaf(fg, cold, ig*gt);
      float hn = og * tanhx(cn);
      ws[WS_C1S + npar*4096 + hidx*16 + b] = cn;
      ws[WS_H1S + npar*4096 + hidx*16 + b] = hn;
      ws[WS_OD + q*4096 + hidx*16 + b] = hn;
      if (q == T_-1){
        out[OUT_HID  + 4096 + b*256 + hidx] = hn;
        out[OUT_CELL + 4096 + b*256 + hidx] = cn;
      }
    }
  }
}

// ---------------- odp2[t*16+b][a] = (od @ W_attn[:,512:768]^T) * 2log2e ----------------
__global__ __launch_bounds__(256) void k_odp(float* __restrict__ ws){
  int row = blockIdx.x;        // 512 = t*16+b
  int t = row >> 4, b = row & 15;
  int tid = threadIdx.x;
  __shared__ float odl[256];
  odl[tid] = ws[WS_OD + t*4096 + tid*16 + b];
  __syncthreads();
  if (tid < 100){
    float acc = 0.f;
    for (int k = 0; k < 256; ++k) acc = fmaf(ws[WS_WODT + k*100 + tid], odl[k], acc);
    ws[WS_ODP2 + row*100 + tid] = acc * L2E2;
  }
}

// ---------------- attention recurrence v3: one WG per batch, cov in registers,
// 2 barriers/step, LDS-atomic reductions with parity double-buffering ----------------
__global__ __launch_bounds__(1024, 4) void k_attn(const float* __restrict__ amask,
    const float* __restrict__ W_attn, const float* __restrict__ wout_g,
    float* __restrict__ out, float* __restrict__ ws){
  int b = blockIdx.x;
  int tid = threadIdx.x;
  int wv = tid >> 6, l = tid & 63;
  int half = wv & 1, sblk = wv >> 1;
  int s = sblk*64 + l;
  bool valid = (s < 400) && (sblk < 7);
  bool even = (half == 0);
  int a0 = half*50;
  __shared__ float eh[2][400];
  __shared__ float4 f4[2][100];
  __shared__ float wcwo[200];
  __shared__ float den[2], cls[2];
  if (tid < 100){
    wcwo[tid]       = W_attn[tid*769 + 768] * L2E2;
    wcwo[100 + tid] = -2.f * wout_g[tid];
  }
  if (tid < 2){ den[tid] = 0.f; cls[tid] = 0.f; }
  __syncthreads();
  float woSum = 0.f;
  #pragma unroll 10
  for (int a = 0; a < 100; ++a) woSum -= 0.5f * wcwo[100 + a];
  float amL = valid ? amask[s*16 + b] * L2E : 0.f;
  float cov = 0.f;
  float ba[50];
  #pragma unroll
  for (int i = 0; i < 50; ++i)
    ba[i] = valid ? ws[WS_BASE2 + (b*100 + a0 + i)*400 + s] : 0.f;
  if (tid < 100){
    float od = ws[WS_ODP2 + b*100 + tid];
    f4[0][tid] = make_float4(od, wcwo[tid], wcwo[100 + tid], 0.f);
  }
  __syncthreads();

  for (int t = 0; t < T_; ++t){
    int par = t & 1;
    if (valid){
      float ep0 = 0.f, ep1 = 0.f;
      #pragma unroll
      for (int i = 0; i < 50; i += 2){
        float4 qa = f4[par][a0 + i];
        float4 qb = f4[par][a0 + i + 1];
        float xa = fmaf(qa.y, cov, ba[i]   + qa.x);
        float xb = fmaf(qb.y, cov, ba[i+1] + qb.x);
        ep0 = fmaf(qa.z, frcp(1.f + fexp2(xa)), ep0);
        ep1 = fmaf(qb.z, frcp(1.f + fexp2(xb)), ep1);
      }
      eh[half][s] = ep0 + ep1;
    }
    __syncthreads();                      // A: eh ready
    float ex = 0.f;
    if (valid){
      float et = woSum + eh[0][s] + eh[1][s];
      ex = fexp2(fmaf(et, L2E, amL));
    }
    float ps = ex;
    #pragma unroll
    for (int m = 32; m >= 1; m >>= 1) ps += __shfl_xor(ps, m);
    if (even && l == 0) atomicAdd(&den[par], ps);
    if (tid < 100 && t < T_-1){
      float od = ws[WS_ODP2 + ((t+1)*16 + b)*100 + tid];
      f4[par^1][tid] = make_float4(od, wcwo[tid], wcwo[100 + tid], 0.f);
    }
    if (tid == 0 && t > 0){
      out[OUT_CL + (t-1)*16 + b] = cls[par^1];
      cls[par^1] = 0.f;
      den[par^1] = 0.f;
    }
    __syncthreads();                      // B: den ready
    float inv = frcp(den[par]);
    float at = ex * inv;
    float cl = fminf(at, cov);
    cov += at;
    float p2 = cl;
    #pragma unroll
    for (int m = 32; m >= 1; m >>= 1) p2 += __shfl_xor(p2, m);
    if (even && l == 0) atomicAdd(&cls[par], p2);
    if (even && valid) ws[WS_ATTN + (b*32 + t)*400 + s] = at;
  }
  __syncthreads();
  if (tid == 0) out[OUT_CL + 31*16 + b] = cls[1];
  if (even && valid) out[OUT_COV + s*16 + b] = cov;
}

// ---------------- context partials into out-scratch: ctxp[sc][t*16+b][512] ----------------
__global__ __launch_bounds__(256) void k_ctx(const float* __restrict__ enc,
    const float* __restrict__ ws, float* __restrict__ ctxp){
  int b = blockIdx.x, jh = blockIdx.y, sc = blockIdx.z;   // (16,2,8)
  int tid = threadIdx.x;
  __shared__ float at[32*52];
  for (int o = tid; o < 1600; o += 256){
    int t = o/50, s2 = o%50;
    at[t*52 + s2] = ws[WS_ATTN + (b*32 + t)*400 + sc*50 + s2];
  }
  __syncthreads();
  int j = jh*256 + tid;
  float acc[32];
  #pragma unroll
  for (int t = 0; t < 32; ++t) acc[t] = 0.f;
  for (int s2 = 0; s2 < 50; ++s2){
    float evv = enc[((sc*50 + s2)*16 + b)*512 + j];
    #pragma unroll
    for (int t = 0; t < 32; ++t) acc[t] = fmaf(at[t*52 + s2], evv, acc[t]);
  }
  #pragma unroll
  for (int t = 0; t < 32; ++t)
    ctxp[sc*CTXP_SZ + (t*16 + b)*512 + j] = acc[t];
}

// ---------------- pgen + h1 (vocab hidden, bf16 padded) per (t,b) ----------------
__global__ __launch_bounds__(256) void k_pgen_h1(const float* __restrict__ input_dec,
    const float* __restrict__ emb, const float* __restrict__ b_v1,
    const float* __restrict__ W_pgen, const float* __restrict__ b_pgen,
    const float* __restrict__ ctxp, float* __restrict__ ws){
  int row = blockIdx.x, tid = threadIdx.x;
  int t = row >> 4, b = row & 15;
  __shared__ float pv[768], el[50], red[16];
  pv[tid] = ws[WS_OD + t*4096 + tid*16 + b];
  float c0 = 0.f, c1 = 0.f;
  #pragma unroll
  for (int sc = 0; sc < 8; ++sc){
    c0 += ctxp[sc*CTXP_SZ + row*512 + tid];
    c1 += ctxp[sc*CTXP_SZ + row*512 + 256 + tid];
  }
  pv[256 + tid] = c0;
  pv[512 + tid] = c1;
  int tok = (int)input_dec[row];
  if (tid < 50) el[tid] = emb[tok*50 + tid];
  __syncthreads();
  float p = 0.f;
  for (int k = tid; k < 818; k += 256){
    float x = (k < 512) ? pv[256 + k] : (k < 768) ? pv[k - 512] : el[k - 768];
    p = fmaf(W_pgen[k], x, p);
  }
  p = bredSum(p, red);
  if (tid == 0) ws[WS_PGEN + row] = sigm(p + b_pgen[0]);
  short* hb = (short*)(ws + WS_H1B);
  if (tid < 100){
    float acc = b_v1[tid];
    for (int k = 0; k < 768; ++k) acc = fmaf(ws[WS_WV1T + k*100 + tid], pv[k], acc);
    hb[row*128 + tid] = cvt_bf16(acc);
  } else if (tid < 128){
    hb[row*128 + tid] = 0;
  }
}

// ---------------- vocab GEMM via MFMA: shared frag loader ----------------
__device__ __forceinline__ void load_bfrags(const float* __restrict__ W_v2,
    const float* __restrict__ b_v2, int v0, int lane_m, int lq,
    bf16x8 bf[4][4], float bias[4], int vv[4]){
  #pragma unroll
  for (int nt = 0; nt < 4; ++nt){
    int v = v0 + nt*16 + lane_m;
    vv[nt] = v;
    bool vok = v < V_;
    bias[nt] = vok ? b_v2[v] : 0.f;
    const float* wp = W_v2 + (size_t)v*100;
    #pragma unroll
    for (int kk = 0; kk < 4; ++kk){
      int k0 = kk*32 + lq*8;
      float x[8];
      if (vok && kk < 3){
        float4 p0 = *(const float4*)(wp + k0);
        float4 p1 = *(const float4*)(wp + k0 + 4);
        x[0]=p0.x; x[1]=p0.y; x[2]=p0.z; x[3]=p0.w;
        x[4]=p1.x; x[5]=p1.y; x[6]=p1.z; x[7]=p1.w;
      } else if (vok && k0 == 96){
        float4 p0 = *(const float4*)(wp + 96);
        x[0]=p0.x; x[1]=p0.y; x[2]=p0.z; x[3]=p0.w;
        x[4]=0.f; x[5]=0.f; x[6]=0.f; x[7]=0.f;
      } else {
        #pragma unroll
        for (int e = 0; e < 8; ++e) x[e] = 0.f;
      }
      bf16x8 r;
      #pragma unroll
      for (int e = 0; e < 8; ++e) r[e] = cvt_bf16(x[e]);
      bf[nt][kk] = r;
    }
  }
}

// ---------------- pass A: per-row exp2-sums of logits (no materialization) ----------------
__global__ __launch_bounds__(256) void k_vsum(const float* __restrict__ W_v2,
    const float* __restrict__ b_v2, float* __restrict__ ws){
  int tid = threadIdx.x;
  int wave = tid >> 6, l = tid & 63;
  int lane_m = l & 15, lq = l >> 4;
  int v0 = blockIdx.x*256 + wave*64;
  int r0base = blockIdx.y*256;
  __shared__ float rsum[256];
  for (int o = tid; o < 256; o += 256) rsum[o] = 0.f;
  bf16x8 bf[4][4];
  float bias[4];
  int vv[4];
  load_bfrags(W_v2, b_v2, v0, lane_m, lq, bf, bias, vv);
  __syncthreads();
  const short* hws = (const short*)(ws + WS_H1B);
  for (int rg = 0; rg < 16; ++rg){
    int r0 = r0base + rg*16;
    bf16x8 af[4];
    #pragma unroll
    for (int kk = 0; kk < 4; ++kk)
      af[kk] = *(const bf16x8*)(hws + (r0 + lane_m)*128 + kk*32 + lq*8);
    float es[4] = {0.f, 0.f, 0.f, 0.f};
    #pragma unroll
    for (int nt = 0; nt < 4; ++nt){
      f32x4 c = {bias[nt], bias[nt], bias[nt], bias[nt]};
      #pragma unroll
      for (int kk = 0; kk < 4; ++kk)
        c = __builtin_amdgcn_mfma_f32_16x16x32_bf16(af[kk], bf[nt][kk], c, 0, 0, 0);
      if (vv[nt] < V_){
        #pragma unroll
        for (int j = 0; j < 4; ++j) es[j] += fexp2(c[j] * L2E);
      }
    }
    #pragma unroll
    for (int m = 1; m <= 8; m <<= 1){
      #pragma unroll
      for (int j = 0; j < 4; ++j) es[j] += __shfl_xor(es[j], m);
    }
    if (lane_m == 0){
      #pragma unroll
      for (int j = 0; j < 4; ++j)
        atomicAdd(&rsum[rg*16 + lq*4 + j], es[j]);
    }
  }
  __syncthreads();
  if (tid < 256) atomicAdd(ws + WS_VSUM + r0base + tid, rsum[tid]);
}

// ---------------- pass B: recompute logits, write softmax*pgen via LDS-staged coalesced stores ----------------
__global__ __launch_bounds__(256) void k_vwrite(const float* __restrict__ W_v2,
    const float* __restrict__ b_v2, const float* __restrict__ ws, float* __restrict__ out){
  int tid = threadIdx.x;
  int wave = tid >> 6, l = tid & 63;
  int lane_m = l & 15, lq = l >> 4;
  int vblock0 = blockIdx.x*256;
  int v0 = vblock0 + wave*64;
  int r0base = blockIdx.y*128;
  __shared__ float scs[128];
  __shared__ float stg[16][260];
  if (tid < 128){
    int r = r0base + tid;
    scs[tid] = ws[WS_PGEN + r] / ws[WS_VSUM + r];
  }
  bf16x8 bf[4][4];
  float bias[4];
  int vv[4];
  load_bfrags(W_v2, b_v2, v0, lane_m, lq, bf, bias, vv);
  __syncthreads();
  const short* hws = (const short*)(ws + WS_H1B);
  int limit = BV_ - vblock0;            // valid col count in [0,256]
  if (limit > 256) limit = 256;
  for (int rg = 0; rg < 8; ++rg){
    int r0 = r0base + rg*16;
    bf16x8 af[4];
    #pragma unroll
    for (int kk = 0; kk < 4; ++kk)
      af[kk] = *(const bf16x8*)(hws + (r0 + lane_m)*128 + kk*32 + lq*8);
    #pragma unroll
    for (int nt = 0; nt < 4; ++nt){
      f32x4 c = {bias[nt], bias[nt], bias[nt], bias[nt]};
      #pragma unroll
      for (int kk = 0; kk < 4; ++kk)
        c = __builtin_amdgcn_mfma_f32_16x16x32_bf16(af[kk], bf[nt][kk], c, 0, 0, 0);
      bool gen = vv[nt] < V_;
      #pragma unroll
      for (int j = 0; j < 4; ++j){
        int rloc = lq*4 + j;
        float p = gen ? fexp2(c[j] * L2E) * scs[rg*16 + rloc] : 0.f;
        stg[rloc][wave*64 + nt*16 + lane_m] = p;
      }
    }
    __syncthreads();
    #pragma unroll
    for (int rep = 0; rep < 4; ++rep){
      int o = rep*256 + tid;
      int rr = o >> 6, c4 = (o & 63)*4;
      size_t base = (size_t)(r0base + rg*16 + rr)*BV_ + vblock0;
      if (c4 + 4 <= limit){
        float4 val = *(const float4*)&stg[rr][c4];
        *(float4*)&out[base + c4] = val;
      } else {
        for (int e = 0; e < 4; ++e)
          if (c4 + e < limit) out[base + c4 + e] = stg[rr][c4 + e];
      }
    }
    __syncthreads();
  }
}

// ---------------- copy-distribution scatter ----------------
__global__ __launch_bounds__(256) void k_scatter(const int* __restrict__ real_index,
    const float* __restrict__ ws, float* __restrict__ out){
  int i = blockIdx.x*256 + threadIdx.x;   // 16*32*400
  int b = i / 12800, r = i % 12800, t = r / 400, s = r % 400;
  float at = ws[WS_ATTN + i];
  float w = 1.f - ws[WS_PGEN + t*16 + b];
  int col = real_index[s*16 + b];
  atomicAdd(out + (size_t)(t*16 + b)*BV_ + col, at*w);
}

extern "C" void kernel_launch(void* const* d_in, const int* in_sizes, int n_in,
                              void* d_out, int out_size, void* d_ws, size_t ws_size,
                              hipStream_t stream){
  const float* output_enc = (const float*)d_in[0];
  const int*   real_index = (const int*)d_in[1];
  const float* input_dec  = (const float*)d_in[3];
  const float* hidden_enc = (const float*)d_in[4];
  const float* cell_enc   = (const float*)d_in[5];
  const float* att_mask   = (const float*)d_in[6];
  const float* emb        = (const float*)d_in[7];
  const float* W_reduce   = (const float*)d_in[8];
  const float* b_reduce   = (const float*)d_in[9];
  const float* w_ih0      = (const float*)d_in[10];
  const float* w_hh0      = (const float*)d_in[11];
  const float* b_ih0      = (const float*)d_in[12];
  const float* b_hh0      = (const float*)d_in[13];
  const float* w_ih1      = (const float*)d_in[14];
  const float* w_hh1      = (const float*)d_in[15];
  const float* b_ih1      = (const float*)d_in[16];
  const float* b_hh1      = (const float*)d_in[17];
  const float* W_attn     = (const float*)d_in[18];
  const float* b_attn     = (const float*)d_in[19];
  const float* w_attn_out = (const float*)d_in[20];
  const float* W_v1       = (const float*)d_in[21];
  const float* b_v1       = (const float*)d_in[22];
  const float* W_v2       = (const float*)d_in[23];
  const float* b_v2       = (const float*)d_in[24];
  const float* W_pgen     = (const float*)d_in[25];
  const float* b_pgen     = (const float*)d_in[26];
  float* out = (float*)d_out;
  float* ws  = (float*)d_ws;
  if (ws_size < (size_t)WS_TOTAL * sizeof(float)) return;

  k_prep<<<dim3(627), dim3(256), 0, stream>>>(w_hh0, w_ih1, w_hh1, W_attn, W_v1, W_reduce, ws);
  k_reduce_enc<<<dim3(32), dim3(256), 0, stream>>>(hidden_enc, cell_enc, b_reduce, ws);
  k_enc_base<<<dim3(25, 2, 16), dim3(256), 0, stream>>>(output_enc, W_attn, b_attn, ws);
  for (int p = 0; p <= T_; ++p)
    k_lstm2<<<dim3(48), dim3(256), 0, stream>>>(input_dec, w_ih0, b_ih0, b_hh0,
                                                b_ih1, b_hh1, ws, out, p);
  k_odp<<<dim3(512), dim3(256), 0, stream>>>(ws);
  k_attn<<<dim3(16), dim3(1024), 0, stream>>>(att_mask, W_attn, w_attn_out, out, ws);
  k_ctx<<<dim3(16, 2, 8), dim3(256), 0, stream>>>(output_enc, ws, out);
  k_pgen_h1<<<dim3(512), dim3(256), 0, stream>>>(input_dec, emb, b_v1, W_pgen, b_pgen, out, ws);
  k_vsum<<<dim3(196, 2), dim3(256), 0, stream>>>(W_v2, b_v2, ws);
  k_vwrite<<<dim3(196, 4), dim3(256), 0, stream>>>(W_v2, b_v2, ws, out);
  k_scatter<<<dim3(800), dim3(256), 0, stream>>>(real_index, ws, out);
}